// Round 7
// baseline (282.487 us; speedup 1.0000x reference)
//
#include <hip/hip_runtime.h>
#include <cstdint>

typedef unsigned short u16;
typedef __attribute__((ext_vector_type(8))) short short8;
typedef __attribute__((ext_vector_type(4))) float floatx4;

#define BT    8192
#define TSEQ  2048
#define NBAT  4
#define CMOD  512
#define NH    4
#define HD    128
#define DFF   2048
#define CQKV  1536

__device__ __forceinline__ u16 f2bf(float f) {
  union { float f; uint32_t u; } v; v.f = f;
  uint32_t r = v.u + 0x7FFFu + ((v.u >> 16) & 1u);
  return (u16)(r >> 16);
}
__device__ __forceinline__ float bf2f(u16 u) {
  union { uint32_t u; float f; } v; v.u = ((uint32_t)u) << 16; return v.f;
}
__device__ __forceinline__ float exp2a(float x) {
  float r; asm("v_exp_f32 %0, %1" : "=v"(r) : "v"(x)); return r;
}
__device__ __forceinline__ float rcpa(float x) {
  float r; asm("v_rcp_f32 %0, %1" : "=v"(r) : "v"(x)); return r;
}

typedef __attribute__((address_space(1))) const unsigned int ga_u32;
typedef __attribute__((address_space(3))) unsigned int ls_u32;
__device__ __forceinline__ void glds16(const u16* g, u16* l) {
  __builtin_amdgcn_global_load_lds((ga_u32*)g, (ls_u32*)l, 16, 0, 0);
}

// ---------------- fused prep: 4 weight transposes + LN1 (frozen) ----------------
__device__ __forceinline__ void tcast_body(const float* __restrict__ W, u16* __restrict__ Wt,
                                           int K, int N, int bx, int by, int tid,
                                           float (*tile)[33]) {
  int n0 = bx * 32, k0 = by * 32;
  int tx = tid & 31, ty = tid >> 5;
  #pragma unroll
  for (int r = 0; r < 32; r += 8)
    tile[r + ty][tx] = W[(size_t)(k0 + r + ty) * N + n0 + tx];
  __syncthreads();
  #pragma unroll
  for (int r = 0; r < 32; r += 8)
    Wt[(size_t)(n0 + r + ty) * K + k0 + tx] = f2bf(tile[tx][r + ty]);
}

__global__ __launch_bounds__(256) void prep_kernel(
    const float* __restrict__ x, const float* __restrict__ g, const float* __restrict__ b,
    const float* __restrict__ wqkv, const float* __restrict__ wproj,
    const float* __restrict__ wff1, const float* __restrict__ wff2,
    u16* __restrict__ ln_out, u16* __restrict__ wqkvT, u16* __restrict__ wprojT,
    u16* __restrict__ wff1T, u16* __restrict__ wff2T) {
  __shared__ float tile[32][33];
  int bid = blockIdx.x, tid = threadIdx.x;
  if (bid < 768) {
    tcast_body(wqkv, wqkvT, CMOD, CQKV, bid % 48, bid / 48, tid, tile);
  } else if (bid < 1024) {
    int id = bid - 768; tcast_body(wproj, wprojT, CMOD, CMOD, id % 16, id / 16, tid, tile);
  } else if (bid < 2048) {
    int id = bid - 1024; tcast_body(wff1, wff1T, CMOD, DFF, id % 64, id / 64, tid, tile);
  } else if (bid < 3072) {
    int id = bid - 2048; tcast_body(wff2, wff2T, DFF, CMOD, id % 16, id / 16, tid, tile);
  } else {
    int row = (bid - 3072) * 4 + (tid >> 6);
    int lane = tid & 63;
    const float4* xr = (const float4*)(x + (size_t)row * CMOD);
    float4 a = xr[lane], c = xr[lane + 64];
    float s = a.x + a.y + a.z + a.w + c.x + c.y + c.z + c.w;
    float q = a.x*a.x + a.y*a.y + a.z*a.z + a.w*a.w
            + c.x*c.x + c.y*c.y + c.z*c.z + c.w*c.w;
    #pragma unroll
    for (int o = 32; o; o >>= 1) { s += __shfl_xor(s, o); q += __shfl_xor(q, o); }
    float mu = s * (1.0f / CMOD);
    float rstd = rsqrtf(q * (1.0f / CMOD) - mu * mu + 1e-5f);
    const float4* gr = (const float4*)g;
    const float4* br = (const float4*)b;
    float4 g0 = gr[lane], g1 = gr[lane + 64], b0 = br[lane], b1 = br[lane + 64];
    u16* orow = ln_out + (size_t)row * CMOD;
    int i0 = lane * 4, i1 = (lane + 64) * 4;
    orow[i0 + 0] = f2bf((a.x - mu) * rstd * g0.x + b0.x);
    orow[i0 + 1] = f2bf((a.y - mu) * rstd * g0.y + b0.y);
    orow[i0 + 2] = f2bf((a.z - mu) * rstd * g0.z + b0.z);
    orow[i0 + 3] = f2bf((a.w - mu) * rstd * g0.w + b0.w);
    orow[i1 + 0] = f2bf((c.x - mu) * rstd * g1.x + b1.x);
    orow[i1 + 1] = f2bf((c.y - mu) * rstd * g1.y + b1.y);
    orow[i1 + 2] = f2bf((c.z - mu) * rstd * g1.z + b1.z);
    orow[i1 + 3] = f2bf((c.w - mu) * rstd * g1.w + b1.w);
  }
}

// ---------------- layernorm (standalone, for LN2; frozen) ----------------
__global__ __launch_bounds__(256) void ln_kernel(const float* __restrict__ x,
                                                 const float* __restrict__ g,
                                                 const float* __restrict__ b,
                                                 u16* __restrict__ out) {
  int row = blockIdx.x * 4 + (threadIdx.x >> 6);
  int lane = threadIdx.x & 63;
  const float4* xr = (const float4*)(x + (size_t)row * CMOD);
  float4 a = xr[lane], c = xr[lane + 64];
  float s = a.x + a.y + a.z + a.w + c.x + c.y + c.z + c.w;
  float q = a.x*a.x + a.y*a.y + a.z*a.z + a.w*a.w
          + c.x*c.x + c.y*c.y + c.z*c.z + c.w*c.w;
  #pragma unroll
  for (int o = 32; o; o >>= 1) { s += __shfl_xor(s, o); q += __shfl_xor(q, o); }
  float mu = s * (1.0f / CMOD);
  float rstd = rsqrtf(q * (1.0f / CMOD) - mu * mu + 1e-5f);
  const float4* gr = (const float4*)g;
  const float4* br = (const float4*)b;
  float4 g0 = gr[lane], g1 = gr[lane + 64], b0 = br[lane], b1 = br[lane + 64];
  u16* orow = out + (size_t)row * CMOD;
  int i0 = lane * 4, i1 = (lane + 64) * 4;
  orow[i0 + 0] = f2bf((a.x - mu) * rstd * g0.x + b0.x);
  orow[i0 + 1] = f2bf((a.y - mu) * rstd * g0.y + b0.y);
  orow[i0 + 2] = f2bf((a.z - mu) * rstd * g0.z + b0.z);
  orow[i0 + 3] = f2bf((a.w - mu) * rstd * g0.w + b0.w);
  orow[i1 + 0] = f2bf((c.x - mu) * rstd * g1.x + b1.x);
  orow[i1 + 1] = f2bf((c.y - mu) * rstd * g1.y + b1.y);
  orow[i1 + 2] = f2bf((c.z - mu) * rstd * g1.z + b1.z);
  orow[i1 + 3] = f2bf((c.w - mu) * rstd * g1.w + b1.w);
}

// ---------------- MFMA GEMM: R6 (frozen, incl. fragment-blocked EPI=0) ----------------
template <int EPI, int TM, int TN, int MINW>
__global__ __launch_bounds__(256, MINW) void gemm_kernel(
    const u16* __restrict__ A, const u16* __restrict__ Bt, int K,
    const float* __restrict__ resid, float* __restrict__ outf,
    u16* __restrict__ ob0, u16* __restrict__ ob1, u16* __restrict__ ob2) {
  constexpr int MR  = TM / 32;
  constexpr int NR  = TN / 32;
  constexpr int NAR = TM / 64;
  constexpr int NBR = TN / 64;
  __shared__ __align__(16) u16 As[2][TM * 32];
  __shared__ __align__(16) u16 Bs[2][TN * 32];
  int tid = threadIdx.x;
  int lane = tid & 63, wave = tid >> 6;
  int lane16 = lane & 15, quad = lane >> 4;
  int m0 = blockIdx.y * TM, n0 = blockIdx.x * TN;
  int wm = (wave >> 1) * (TM / 2), wn = (wave & 1) * (TN / 2);

  floatx4 acc[MR][NR];
  #pragma unroll
  for (int i = 0; i < MR; i++)
    #pragma unroll
    for (int j = 0; j < NR; j++) acc[i][j] = (floatx4)(0.0f);

  const u16* agp[NAR]; u16* alp[NAR][2];
  const u16* bgp[NBR]; u16* blp[NBR][2];
  #pragma unroll
  for (int i = 0; i < NAR; i++) {
    int s = i * 256 + tid;
    agp[i] = A + (size_t)(m0 + (s >> 2)) * K + (s & 3) * 8;
    alp[i][0] = &As[0][(i * 256 + wave * 64) * 8];
    alp[i][1] = &As[1][(i * 256 + wave * 64) * 8];
  }
  #pragma unroll
  for (int i = 0; i < NBR; i++) {
    int s = i * 256 + tid;
    bgp[i] = Bt + (size_t)(n0 + (s >> 2)) * K + (s & 3) * 8;
    blp[i][0] = &Bs[0][(i * 256 + wave * 64) * 8];
    blp[i][1] = &Bs[1][(i * 256 + wave * 64) * 8];
  }

  int nk = K >> 5;
  #pragma unroll
  for (int i = 0; i < NAR; i++) glds16(agp[i], alp[i][0]);
  #pragma unroll
  for (int i = 0; i < NBR; i++) glds16(bgp[i], blp[i][0]);

  for (int kt = 0; kt < nk; kt++) {
    __syncthreads();
    int buf = kt & 1;
    if (kt + 1 < nk) {
      int k1 = (kt + 1) * 32;
      #pragma unroll
      for (int i = 0; i < NAR; i++) glds16(agp[i] + k1, alp[i][buf ^ 1]);
      #pragma unroll
      for (int i = 0; i < NBR; i++) glds16(bgp[i] + k1, blp[i][buf ^ 1]);
    }
    short8 af[MR];
    #pragma unroll
    for (int i = 0; i < MR; i++)
      af[i] = *(const short8*)&As[buf][(wm + i * 16 + lane16) * 32 + quad * 8];
    #pragma unroll
    for (int j = 0; j < NR; j++) {
      short8 bfj = *(const short8*)&Bs[buf][(wn + j * 16 + lane16) * 32 + quad * 8];
      #pragma unroll
      for (int i = 0; i < MR; i++)
        acc[i][j] = __builtin_amdgcn_mfma_f32_16x16x32_bf16(af[i], bfj, acc[i][j], 0, 0, 0);
    }
  }

  #pragma unroll
  for (int i = 0; i < MR; i++) {
    #pragma unroll
    for (int j = 0; j < NR; j++) {
      #pragma unroll
      for (int r = 0; r < 4; r++) {
        int m = m0 + wm + i * 16 + quad * 4 + r;
        int n = n0 + wn + j * 16 + lane16;
        float v = acc[i][j][r];
        if (EPI == 0) {
          int bb = m >> 11, t = m & 2047;
          int nn = n & 511, which = n >> 9;
          int h = nn >> 7, d = nn & 127;
          size_t base = (size_t)(bb * NH + h) * 262144;
          if (which == 0) {
            int t16 = t >> 4, l16 = t & 15, cc = d >> 5, qd = (d >> 3) & 3, e = d & 7;
            ob0[base + (size_t)((t16 * 16 + cc * 4 + qd) * 128 + l16 * 8 + e)] = f2bf(v * 0.12751743f);
          } else if (which == 1) {
            int kt = t >> 5, hf = (t >> 4) & 1, l16 = t & 15, cc = d >> 5, qd = (d >> 3) & 3, e = d & 7;
            ob1[base + (size_t)((kt * 8 + hf * 4 + cc) * 512 + qd * 128 + l16 * 8 + e)] = f2bf(v);
          } else {
            int kt = t >> 5, qv = (t >> 3) & 3, e = t & 7, j2 = d >> 4, l16 = d & 15;
            ob2[base + (size_t)((kt * 8 + j2) * 512 + qv * 128 + l16 * 8 + e)] = f2bf(v);
          }
        } else if (EPI == 1) {
          size_t idx = (size_t)m * CMOD + n;
          outf[idx] = v + resid[idx];
        } else if (EPI == 2) {
          float ge = 0.5f * v * (1.0f + erff(v * 0.70710678118654752f));
          ob0[(size_t)m * DFF + n] = f2bf(ge);
        } else {
          size_t idx = (size_t)m * CMOD + n;
          outf[idx] = v + resid[idx];
        }
      }
    }
  }
}

// ---------------- flash attention: + in-register K/V double-buffer (THE ONLY CHANGE) ----------------
// R6 post-mortem: staging overhead removed (VALU 44->28, conflicts -3x) but dur flat
// -> bottleneck is exposed load latency on the serial per-iter chain (~2100cy/iter
// at ~6 waves/CU avg). Fix: ping-pong register sets tA/tB (statically named, 2x
// unrolled loop): loads for kt+1 issue at top of iter kt, compute kt runs entirely
// from registers -> ~350cy compute covers ~400cy L2 latency. Same addresses, same
// values, same MFMA order -> bit-identical output.
struct KVr { short8 k0[4], k1[4], v[8]; };

__device__ __forceinline__ void ldkv(KVr& t, const u16* __restrict__ Kb,
                                     const u16* __restrict__ Vb, int kt, int lane) {
  const u16* kp = Kb + (size_t)kt * 4096 + lane * 8;
  const u16* vp = Vb + (size_t)kt * 4096 + lane * 8;
  #pragma unroll
  for (int cc = 0; cc < 4; cc++) {
    t.k0[cc] = *(const short8*)&kp[cc * 512];
    t.k1[cc] = *(const short8*)&kp[(4 + cc) * 512];
  }
  #pragma unroll
  for (int j = 0; j < 8; j++)
    t.v[j] = *(const short8*)&vp[j * 512];
}

__global__ __launch_bounds__(256) void attn_kernel(const u16* __restrict__ qb,
                                                   const u16* __restrict__ kb,
                                                   const u16* __restrict__ vtb,
                                                   u16* __restrict__ po,
                                                   float* __restrict__ pl) {
  int tid = threadIdx.x, wave = tid >> 6, lane = tid & 63;
  int lane16 = lane & 15, quad = lane >> 4;
  int bh = blockIdx.x;
  int cid = 79 - (int)blockIdx.y;  // heavy chunks dispatch first
  int qt, c;
  if (cid < 8)       { qt = cid;                    c = 0; }
  else if (cid < 24) { qt = 8 + ((cid - 8) >> 1);   c = (cid - 8) & 1; }
  else if (cid < 48) { qt = 16 + (cid - 24) / 3;    c = (cid - 24) % 3; }
  else               { qt = 24 + ((cid - 48) >> 2); c = (cid - 48) & 3; }

  int q0w = qt * 64 + wave * 16;
  const u16* Qb = qb  + (size_t)bh * 262144;
  const u16* Kb = kb  + (size_t)bh * 262144;
  const u16* Vb = vtb + (size_t)bh * 262144;

  short8 aq[4];
  #pragma unroll
  for (int cc = 0; cc < 4; cc++)
    aq[cc] = *(const short8*)&Qb[(size_t)(((q0w >> 4) * 16 + cc * 4 + quad) * 128 + lane16 * 8)];

  int ktw   = (q0w >> 5) + 1;
  int ktblk = qt * 2 + 2;
  int kt0   = c * 16;
  int kend  = min(min(kt0 + 16, ktblk), ktw);

  floatx4 o[8];
  #pragma unroll
  for (int j = 0; j < 8; j++) o[j] = (floatx4)(0.0f);
  floatx4 ol = (floatx4)(0.0f);

  short8 ones;
  #pragma unroll
  for (int e = 0; e < 8; e++) ones[e] = (short)0x3F80;

  int addrA = (lane16 + ((quad & 1) << 5)) << 2;
  int addrB = addrA + 64;
  int q_g = q0w + lane16;

  KVr tA, tB;

#define ATTN_STEP(T, KT)                                                                            \
  {                                                                                                 \
    floatx4 st0 = (floatx4)(0.0f), st1 = (floatx4)(0.0f);                                           \
    _Pragma("unroll")                                                                               \
    for (int cc = 0; cc < 4; cc++) {                                                                \
      st0 = __builtin_amdgcn_mfma_f32_16x16x32_bf16(T.k0[cc], aq[cc], st0, 0, 0, 0);                \
      st1 = __builtin_amdgcn_mfma_f32_16x16x32_bf16(T.k1[cc], aq[cc], st1, 0, 0, 0);                \
    }                                                                                               \
    int k0b = (KT) * 32 + quad * 4;                                                                 \
    _Pragma("unroll")                                                                               \
    for (int r = 0; r < 4; r++) {                                                                   \
      float p0 = exp2a(st0[r]);                                                                     \
      float p1 = exp2a(st1[r]);                                                                     \
      if (k0b + r > q_g) p0 = 0.0f;                                                                 \
      if (k0b + r + 16 > q_g) p1 = 0.0f;                                                            \
      st0[r] = p0; st1[r] = p1;                                                                     \
    }                                                                                               \
    uint32_t x0 = __builtin_amdgcn_perm(__float_as_uint(st0[1]), __float_as_uint(st0[0]), 0x07060302u); \
    uint32_t x1 = __builtin_amdgcn_perm(__float_as_uint(st0[3]), __float_as_uint(st0[2]), 0x07060302u); \
    uint32_t y0 = __builtin_amdgcn_perm(__float_as_uint(st1[1]), __float_as_uint(st1[0]), 0x07060302u); \
    uint32_t y1 = __builtin_amdgcn_perm(__float_as_uint(st1[3]), __float_as_uint(st1[2]), 0x07060302u); \
    int pAx0 = __builtin_amdgcn_ds_bpermute(addrA, (int)x0);                                        \
    int pAx1 = __builtin_amdgcn_ds_bpermute(addrA, (int)x1);                                        \
    int pBx0 = __builtin_amdgcn_ds_bpermute(addrB, (int)x0);                                        \
    int pBx1 = __builtin_amdgcn_ds_bpermute(addrB, (int)x1);                                        \
    int pAy0 = __builtin_amdgcn_ds_bpermute(addrA, (int)y0);                                        \
    int pAy1 = __builtin_amdgcn_ds_bpermute(addrA, (int)y1);                                        \
    int pBy0 = __builtin_amdgcn_ds_bpermute(addrB, (int)y0);                                        \
    int pBy1 = __builtin_amdgcn_ds_bpermute(addrB, (int)y1);                                        \
    union { uint32_t u[4]; short8 s; } pf;                                                          \
    bool hi = quad >= 2;                                                                            \
    pf.u[0] = (uint32_t)(hi ? pAy0 : pAx0);                                                         \
    pf.u[1] = (uint32_t)(hi ? pAy1 : pAx1);                                                         \
    pf.u[2] = (uint32_t)(hi ? pBy0 : pBx0);                                                         \
    pf.u[3] = (uint32_t)(hi ? pBy1 : pBx1);                                                         \
    _Pragma("unroll")                                                                               \
    for (int j = 0; j < 8; j++)                                                                     \
      o[j] = __builtin_amdgcn_mfma_f32_16x16x32_bf16(pf.s, T.v[j], o[j], 0, 0, 0);                  \
    ol = __builtin_amdgcn_mfma_f32_16x16x32_bf16(pf.s, ones, ol, 0, 0, 0);                          \
  }

  ldkv(tA, Kb, Vb, kt0, lane);
  int kt = kt0;
  while (kt < kend) {
    if (kt + 1 < kend) ldkv(tB, Kb, Vb, kt + 1, lane);
    ATTN_STEP(tA, kt);
    kt++;
    if (kt >= kend) break;
    if (kt + 1 < kend) ldkv(tA, Kb, Vb, kt + 1, lane);
    ATTN_STEP(tB, kt);
    kt++;
  }
#undef ATTN_STEP

  int slot = (bh * 32 + qt) * 4 + c;
  u16* pob = po + (size_t)slot * 8192;
  #pragma unroll
  for (int r = 0; r < 4; r++) {
    int qr = wave * 16 + quad * 4 + r;
    #pragma unroll
    for (int j = 0; j < 8; j++)
      pob[qr * 128 + j * 16 + lane16] = f2bf(o[j][r]);
    if (lane16 == 0) pl[slot * 64 + qr] = ol[r];
  }
}

// ---------------- reduce: VERBATIM (frozen) ----------------
__global__ __launch_bounds__(256) void reduce_kernel(const u16* __restrict__ po,
                                                     const float* __restrict__ pl,
                                                     u16* __restrict__ attn) {
  int bh = blockIdx.x >> 5, qt = blockIdx.x & 31;
  int tid = threadIdx.x;
  int nch = (2 * qt + 17) >> 4;
  int qrow = tid >> 2;
  int d0 = (tid & 3) * 32;
  float acc[32];
  #pragma unroll
  for (int i = 0; i < 32; i++) acc[i] = 0.0f;
  float l = 0.0f;
  int slot0 = (bh * 32 + qt) * 4;
  for (int c = 0; c < nch; c++) {
    int slot = slot0 + c;
    l += pl[slot * 64 + qrow];
    const short8* p = (const short8*)(po + (size_t)slot * 8192 + qrow * 128 + d0);
    #pragma unroll
    for (int v = 0; v < 4; v++) {
      short8 pk = p[v];
      #pragma unroll
      for (int e = 0; e < 8; e++) acc[v * 8 + e] += bf2f((u16)pk[e]);
    }
  }
  float inv = rcpa(l);
  int b = bh >> 2, h = bh & 3, t = qt * 64 + qrow;
  u16* orow = attn + ((size_t)(b * TSEQ + t)) * CMOD + h * HD + d0;
  #pragma unroll
  for (int v = 0; v < 4; v++) {
    short8 ov;
    #pragma unroll
    for (int e = 0; e < 8; e++) ov[e] = (short)f2bf(acc[v * 8 + e] * inv);
    *(short8*)(orow + v * 8) = ov;
  }
}

extern "C" void kernel_launch(void* const* d_in, const int* in_sizes, int n_in,
                              void* d_out, int out_size, void* d_ws, size_t ws_size,
                              hipStream_t stream) {
  const float* x     = (const float*)d_in[0];
  const float* ln1g  = (const float*)d_in[1];
  const float* ln1b  = (const float*)d_in[2];
  const float* wqkv  = (const float*)d_in[3];
  const float* wproj = (const float*)d_in[4];
  const float* ln2g  = (const float*)d_in[5];
  const float* ln2b  = (const float*)d_in[6];
  const float* wff1  = (const float*)d_in[7];
  const float* wff2  = (const float*)d_in[8];
  float* out = (float*)d_out;
  char* ws = (char*)d_ws;

  u16* wt_qkv  = (u16*)(ws);
  u16* wt_proj = (u16*)(ws + 1572864);
  u16* wt_ff1  = (u16*)(ws + 2097152);
  u16* wt_ff2  = (u16*)(ws + 4194304);
  u16* ln_buf  = (u16*)(ws + 6291456);
  u16* q_buf   = (u16*)(ws + 14680064);
  u16* k_buf   = (u16*)(ws + 23068672);
  u16* vt_buf  = (u16*)(ws + 31457280);
  u16* attn    = (u16*)(ws + 39845888);
  float* x2    = (float*)(ws + 48234496);
  u16* h1      = (u16*)(ws + 65011712);
  u16* po      = (u16*)(ws + 48234496);
  float* pl    = (float*)(ws + 81788928);

  dim3 blk(256);
  prep_kernel<<<dim3(5120), blk, 0, stream>>>(x, ln1g, ln1b, wqkv, wproj, wff1, wff2,
                                              ln_buf, wt_qkv, wt_proj, wt_ff1, wt_ff2);

  // QKV: TM=128,TN=64, grid 24x64 = 1536 blocks
  gemm_kernel<0, 128, 64, 6><<<dim3(CQKV / 64, BT / 128), blk, 0, stream>>>(
      ln_buf, wt_qkv, CMOD, nullptr, nullptr, q_buf, k_buf, vt_buf);

  attn_kernel<<<dim3(NBAT * NH, 80), blk, 0, stream>>>(q_buf, k_buf, vt_buf, po, pl);

  reduce_kernel<<<dim3(512), blk, 0, stream>>>(po, pl, attn);

  // proj: TM=128,TN=64, grid 8x64 = 512 blocks
  gemm_kernel<1, 128, 64, 4><<<dim3(CMOD / 64, BT / 128), blk, 0, stream>>>(
      attn, wt_proj, CMOD, x, x2, nullptr, nullptr, nullptr);

  ln_kernel<<<dim3(BT / 4), blk, 0, stream>>>(x2, ln2g, ln2b, ln_buf);

  // FF1: TM=128,TN=64, grid 32x64 = 2048 blocks
  gemm_kernel<2, 128, 64, 6><<<dim3(DFF / 64, BT / 128), blk, 0, stream>>>(
      ln_buf, wt_ff1, CMOD, nullptr, nullptr, h1, nullptr, nullptr);

  // FF2: TM=128,TN=64, grid 8x64 = 512 blocks
  gemm_kernel<3, 128, 64, 4><<<dim3(CMOD / 64, BT / 128), blk, 0, stream>>>(
      h1, wt_ff2, DFF, x2, out, nullptr, nullptr, nullptr);
}

// Round 9
// 273.658 us; speedup vs baseline: 1.0323x; 1.0323x over previous
//
#include <hip/hip_runtime.h>
#include <cstdint>

typedef unsigned short u16;
typedef __attribute__((ext_vector_type(8))) short short8;
typedef __attribute__((ext_vector_type(4))) float floatx4;

#define BT    8192
#define TSEQ  2048
#define NBAT  4
#define CMOD  512
#define NH    4
#define HD    128
#define DFF   2048
#define CQKV  1536

__device__ __forceinline__ u16 f2bf(float f) {
  union { float f; uint32_t u; } v; v.f = f;
  uint32_t r = v.u + 0x7FFFu + ((v.u >> 16) & 1u);
  return (u16)(r >> 16);
}
__device__ __forceinline__ float bf2f(u16 u) {
  union { uint32_t u; float f; } v; v.u = ((uint32_t)u) << 16; return v.f;
}
__device__ __forceinline__ float exp2a(float x) {
  float r; asm("v_exp_f32 %0, %1" : "=v"(r) : "v"(x)); return r;
}
__device__ __forceinline__ float rcpa(float x) {
  float r; asm("v_rcp_f32 %0, %1" : "=v"(r) : "v"(x)); return r;
}

typedef __attribute__((address_space(1))) const unsigned int ga_u32;
typedef __attribute__((address_space(3))) unsigned int ls_u32;
__device__ __forceinline__ void glds16(const u16* g, u16* l) {
  __builtin_amdgcn_global_load_lds((ga_u32*)g, (ls_u32*)l, 16, 0, 0);
}

// ---------------- fused prep: 4 weight transposes + LN1 (frozen) ----------------
__device__ __forceinline__ void tcast_body(const float* __restrict__ W, u16* __restrict__ Wt,
                                           int K, int N, int bx, int by, int tid,
                                           float (*tile)[33]) {
  int n0 = bx * 32, k0 = by * 32;
  int tx = tid & 31, ty = tid >> 5;
  #pragma unroll
  for (int r = 0; r < 32; r += 8)
    tile[r + ty][tx] = W[(size_t)(k0 + r + ty) * N + n0 + tx];
  __syncthreads();
  #pragma unroll
  for (int r = 0; r < 32; r += 8)
    Wt[(size_t)(n0 + r + ty) * K + k0 + tx] = f2bf(tile[tx][r + ty]);
}

__global__ __launch_bounds__(256) void prep_kernel(
    const float* __restrict__ x, const float* __restrict__ g, const float* __restrict__ b,
    const float* __restrict__ wqkv, const float* __restrict__ wproj,
    const float* __restrict__ wff1, const float* __restrict__ wff2,
    u16* __restrict__ ln_out, u16* __restrict__ wqkvT, u16* __restrict__ wprojT,
    u16* __restrict__ wff1T, u16* __restrict__ wff2T) {
  __shared__ float tile[32][33];
  int bid = blockIdx.x, tid = threadIdx.x;
  if (bid < 768) {
    tcast_body(wqkv, wqkvT, CMOD, CQKV, bid % 48, bid / 48, tid, tile);
  } else if (bid < 1024) {
    int id = bid - 768; tcast_body(wproj, wprojT, CMOD, CMOD, id % 16, id / 16, tid, tile);
  } else if (bid < 2048) {
    int id = bid - 1024; tcast_body(wff1, wff1T, CMOD, DFF, id % 64, id / 64, tid, tile);
  } else if (bid < 3072) {
    int id = bid - 2048; tcast_body(wff2, wff2T, DFF, CMOD, id % 16, id / 16, tid, tile);
  } else {
    int row = (bid - 3072) * 4 + (tid >> 6);
    int lane = tid & 63;
    const float4* xr = (const float4*)(x + (size_t)row * CMOD);
    float4 a = xr[lane], c = xr[lane + 64];
    float s = a.x + a.y + a.z + a.w + c.x + c.y + c.z + c.w;
    float q = a.x*a.x + a.y*a.y + a.z*a.z + a.w*a.w
            + c.x*c.x + c.y*c.y + c.z*c.z + c.w*c.w;
    #pragma unroll
    for (int o = 32; o; o >>= 1) { s += __shfl_xor(s, o); q += __shfl_xor(q, o); }
    float mu = s * (1.0f / CMOD);
    float rstd = rsqrtf(q * (1.0f / CMOD) - mu * mu + 1e-5f);
    const float4* gr = (const float4*)g;
    const float4* br = (const float4*)b;
    float4 g0 = gr[lane], g1 = gr[lane + 64], b0 = br[lane], b1 = br[lane + 64];
    u16* orow = ln_out + (size_t)row * CMOD;
    int i0 = lane * 4, i1 = (lane + 64) * 4;
    orow[i0 + 0] = f2bf((a.x - mu) * rstd * g0.x + b0.x);
    orow[i0 + 1] = f2bf((a.y - mu) * rstd * g0.y + b0.y);
    orow[i0 + 2] = f2bf((a.z - mu) * rstd * g0.z + b0.z);
    orow[i0 + 3] = f2bf((a.w - mu) * rstd * g0.w + b0.w);
    orow[i1 + 0] = f2bf((c.x - mu) * rstd * g1.x + b1.x);
    orow[i1 + 1] = f2bf((c.y - mu) * rstd * g1.y + b1.y);
    orow[i1 + 2] = f2bf((c.z - mu) * rstd * g1.z + b1.z);
    orow[i1 + 3] = f2bf((c.w - mu) * rstd * g1.w + b1.w);
  }
}

// ---------------- layernorm (standalone, for LN2; frozen) ----------------
__global__ __launch_bounds__(256) void ln_kernel(const float* __restrict__ x,
                                                 const float* __restrict__ g,
                                                 const float* __restrict__ b,
                                                 u16* __restrict__ out) {
  int row = blockIdx.x * 4 + (threadIdx.x >> 6);
  int lane = threadIdx.x & 63;
  const float4* xr = (const float4*)(x + (size_t)row * CMOD);
  float4 a = xr[lane], c = xr[lane + 64];
  float s = a.x + a.y + a.z + a.w + c.x + c.y + c.z + c.w;
  float q = a.x*a.x + a.y*a.y + a.z*a.z + a.w*a.w
          + c.x*c.x + c.y*c.y + c.z*c.z + c.w*c.w;
  #pragma unroll
  for (int o = 32; o; o >>= 1) { s += __shfl_xor(s, o); q += __shfl_xor(q, o); }
  float mu = s * (1.0f / CMOD);
  float rstd = rsqrtf(q * (1.0f / CMOD) - mu * mu + 1e-5f);
  const float4* gr = (const float4*)g;
  const float4* br = (const float4*)b;
  float4 g0 = gr[lane], g1 = gr[lane + 64], b0 = br[lane], b1 = br[lane + 64];
  u16* orow = out + (size_t)row * CMOD;
  int i0 = lane * 4, i1 = (lane + 64) * 4;
  orow[i0 + 0] = f2bf((a.x - mu) * rstd * g0.x + b0.x);
  orow[i0 + 1] = f2bf((a.y - mu) * rstd * g0.y + b0.y);
  orow[i0 + 2] = f2bf((a.z - mu) * rstd * g0.z + b0.z);
  orow[i0 + 3] = f2bf((a.w - mu) * rstd * g0.w + b0.w);
  orow[i1 + 0] = f2bf((c.x - mu) * rstd * g1.x + b1.x);
  orow[i1 + 1] = f2bf((c.y - mu) * rstd * g1.y + b1.y);
  orow[i1 + 2] = f2bf((c.z - mu) * rstd * g1.z + b1.z);
  orow[i1 + 3] = f2bf((c.w - mu) * rstd * g1.w + b1.w);
}

// ---------------- MFMA GEMM: R6 (frozen, incl. fragment-blocked EPI=0) ----------------
template <int EPI, int TM, int TN, int MINW>
__global__ __launch_bounds__(256, MINW) void gemm_kernel(
    const u16* __restrict__ A, const u16* __restrict__ Bt, int K,
    const float* __restrict__ resid, float* __restrict__ outf,
    u16* __restrict__ ob0, u16* __restrict__ ob1, u16* __restrict__ ob2) {
  constexpr int MR  = TM / 32;
  constexpr int NR  = TN / 32;
  constexpr int NAR = TM / 64;
  constexpr int NBR = TN / 64;
  __shared__ __align__(16) u16 As[2][TM * 32];
  __shared__ __align__(16) u16 Bs[2][TN * 32];
  int tid = threadIdx.x;
  int lane = tid & 63, wave = tid >> 6;
  int lane16 = lane & 15, quad = lane >> 4;
  int m0 = blockIdx.y * TM, n0 = blockIdx.x * TN;
  int wm = (wave >> 1) * (TM / 2), wn = (wave & 1) * (TN / 2);

  floatx4 acc[MR][NR];
  #pragma unroll
  for (int i = 0; i < MR; i++)
    #pragma unroll
    for (int j = 0; j < NR; j++) acc[i][j] = (floatx4)(0.0f);

  const u16* agp[NAR]; u16* alp[NAR][2];
  const u16* bgp[NBR]; u16* blp[NBR][2];
  #pragma unroll
  for (int i = 0; i < NAR; i++) {
    int s = i * 256 + tid;
    agp[i] = A + (size_t)(m0 + (s >> 2)) * K + (s & 3) * 8;
    alp[i][0] = &As[0][(i * 256 + wave * 64) * 8];
    alp[i][1] = &As[1][(i * 256 + wave * 64) * 8];
  }
  #pragma unroll
  for (int i = 0; i < NBR; i++) {
    int s = i * 256 + tid;
    bgp[i] = Bt + (size_t)(n0 + (s >> 2)) * K + (s & 3) * 8;
    blp[i][0] = &Bs[0][(i * 256 + wave * 64) * 8];
    blp[i][1] = &Bs[1][(i * 256 + wave * 64) * 8];
  }

  int nk = K >> 5;
  #pragma unroll
  for (int i = 0; i < NAR; i++) glds16(agp[i], alp[i][0]);
  #pragma unroll
  for (int i = 0; i < NBR; i++) glds16(bgp[i], blp[i][0]);

  for (int kt = 0; kt < nk; kt++) {
    __syncthreads();
    int buf = kt & 1;
    if (kt + 1 < nk) {
      int k1 = (kt + 1) * 32;
      #pragma unroll
      for (int i = 0; i < NAR; i++) glds16(agp[i] + k1, alp[i][buf ^ 1]);
      #pragma unroll
      for (int i = 0; i < NBR; i++) glds16(bgp[i] + k1, blp[i][buf ^ 1]);
    }
    short8 af[MR];
    #pragma unroll
    for (int i = 0; i < MR; i++)
      af[i] = *(const short8*)&As[buf][(wm + i * 16 + lane16) * 32 + quad * 8];
    #pragma unroll
    for (int j = 0; j < NR; j++) {
      short8 bfj = *(const short8*)&Bs[buf][(wn + j * 16 + lane16) * 32 + quad * 8];
      #pragma unroll
      for (int i = 0; i < MR; i++)
        acc[i][j] = __builtin_amdgcn_mfma_f32_16x16x32_bf16(af[i], bfj, acc[i][j], 0, 0, 0);
    }
  }

  #pragma unroll
  for (int i = 0; i < MR; i++) {
    #pragma unroll
    for (int j = 0; j < NR; j++) {
      #pragma unroll
      for (int r = 0; r < 4; r++) {
        int m = m0 + wm + i * 16 + quad * 4 + r;
        int n = n0 + wn + j * 16 + lane16;
        float v = acc[i][j][r];
        if (EPI == 0) {
          int bb = m >> 11, t = m & 2047;
          int nn = n & 511, which = n >> 9;
          int h = nn >> 7, d = nn & 127;
          size_t base = (size_t)(bb * NH + h) * 262144;
          if (which == 0) {
            int t16 = t >> 4, l16 = t & 15, cc = d >> 5, qd = (d >> 3) & 3, e = d & 7;
            ob0[base + (size_t)((t16 * 16 + cc * 4 + qd) * 128 + l16 * 8 + e)] = f2bf(v * 0.12751743f);
          } else if (which == 1) {
            int kt = t >> 5, hf = (t >> 4) & 1, l16 = t & 15, cc = d >> 5, qd = (d >> 3) & 3, e = d & 7;
            ob1[base + (size_t)((kt * 8 + hf * 4 + cc) * 512 + qd * 128 + l16 * 8 + e)] = f2bf(v);
          } else {
            int kt = t >> 5, qv = (t >> 3) & 3, e = t & 7, j2 = d >> 4, l16 = d & 15;
            ob2[base + (size_t)((kt * 8 + j2) * 512 + qv * 128 + l16 * 8 + e)] = f2bf(v);
          }
        } else if (EPI == 1) {
          size_t idx = (size_t)m * CMOD + n;
          outf[idx] = v + resid[idx];
        } else if (EPI == 2) {
          float ge = 0.5f * v * (1.0f + erff(v * 0.70710678118654752f));
          ob0[(size_t)m * DFF + n] = f2bf(ge);
        } else {
          size_t idx = (size_t)m * CMOD + n;
          outf[idx] = v + resid[idx];
        }
      }
    }
  }
}

// ---------------- flash attention: R6-exact compute + XCD-locality swizzle (FIXED) ----------------
// R8 bug: bh has only NBAT*NH = 16 values; "bh = n & 31" over grid 2560 launched
// 1280 phantom blocks (bh 16..31) whose po-slot writes (>= 2048) clobbered pl/h1.
// Fixed: grid 1280 = 16 bh x 80 chunks, bh = n & 15, cid = 79 - (n >> 4).
// Swizzle property: all 80 blocks of a bh share n%8 = bh%8 -> one XCD (round-robin
// heuristic); 2 bh/XCD -> K+V+Q = 3MB < 4MB local L2. Compute byte-identical to R6.
__global__ __launch_bounds__(256) void attn_kernel(const u16* __restrict__ qb,
                                                   const u16* __restrict__ kb,
                                                   const u16* __restrict__ vtb,
                                                   u16* __restrict__ po,
                                                   float* __restrict__ pl) {
  int tid = threadIdx.x, wave = tid >> 6, lane = tid & 63;
  int lane16 = lane & 15, quad = lane >> 4;
  int n1d = blockIdx.x;
  int bh = n1d & 15;
  int cid = 79 - (n1d >> 4);   // heavy chunks dispatch first
  int qt, c;
  if (cid < 8)       { qt = cid;                    c = 0; }
  else if (cid < 24) { qt = 8 + ((cid - 8) >> 1);   c = (cid - 8) & 1; }
  else if (cid < 48) { qt = 16 + (cid - 24) / 3;    c = (cid - 24) % 3; }
  else               { qt = 24 + ((cid - 48) >> 2); c = (cid - 48) & 3; }

  int q0w = qt * 64 + wave * 16;
  const u16* Qb = qb  + (size_t)bh * 262144;
  const u16* Kb = kb  + (size_t)bh * 262144;
  const u16* Vb = vtb + (size_t)bh * 262144;

  short8 aq[4];
  #pragma unroll
  for (int cc = 0; cc < 4; cc++)
    aq[cc] = *(const short8*)&Qb[(size_t)(((q0w >> 4) * 16 + cc * 4 + quad) * 128 + lane16 * 8)];

  int ktw   = (q0w >> 5) + 1;
  int ktblk = qt * 2 + 2;
  int kt0   = c * 16;
  int kend  = min(min(kt0 + 16, ktblk), ktw);

  floatx4 o[8];
  #pragma unroll
  for (int j = 0; j < 8; j++) o[j] = (floatx4)(0.0f);
  floatx4 ol = (floatx4)(0.0f);

  short8 ones;
  #pragma unroll
  for (int e = 0; e < 8; e++) ones[e] = (short)0x3F80;

  int addrA = (lane16 + ((quad & 1) << 5)) << 2;
  int addrB = addrA + 64;
  int q_g = q0w + lane16;

  const u16* kp = Kb + (size_t)kt0 * 4096 + lane * 8;
  const u16* vp = Vb + (size_t)kt0 * 4096 + lane * 8;

  for (int kt = kt0; kt < kend; kt++) {
    short8 k0f[4], k1f[4];
    #pragma unroll
    for (int cc = 0; cc < 4; cc++) {
      k0f[cc] = *(const short8*)&kp[cc * 512];
      k1f[cc] = *(const short8*)&kp[(4 + cc) * 512];
    }

    floatx4 st0 = (floatx4)(0.0f), st1 = (floatx4)(0.0f);
    #pragma unroll
    for (int cc = 0; cc < 4; cc++) {
      st0 = __builtin_amdgcn_mfma_f32_16x16x32_bf16(k0f[cc], aq[cc], st0, 0, 0, 0);
      st1 = __builtin_amdgcn_mfma_f32_16x16x32_bf16(k1f[cc], aq[cc], st1, 0, 0, 0);
    }

    short8 vfr[8];
    #pragma unroll
    for (int j = 0; j < 8; j++)
      vfr[j] = *(const short8*)&vp[j * 512];

    int k0b = kt * 32 + quad * 4;
    #pragma unroll
    for (int r = 0; r < 4; r++) {
      float p0 = exp2a(st0[r]);
      float p1 = exp2a(st1[r]);
      if (k0b + r > q_g) p0 = 0.0f;
      if (k0b + r + 16 > q_g) p1 = 0.0f;
      st0[r] = p0; st1[r] = p1;
    }
    uint32_t x0 = __builtin_amdgcn_perm(__float_as_uint(st0[1]), __float_as_uint(st0[0]), 0x07060302u);
    uint32_t x1 = __builtin_amdgcn_perm(__float_as_uint(st0[3]), __float_as_uint(st0[2]), 0x07060302u);
    uint32_t y0 = __builtin_amdgcn_perm(__float_as_uint(st1[1]), __float_as_uint(st1[0]), 0x07060302u);
    uint32_t y1 = __builtin_amdgcn_perm(__float_as_uint(st1[3]), __float_as_uint(st1[2]), 0x07060302u);

    int pAx0 = __builtin_amdgcn_ds_bpermute(addrA, (int)x0);
    int pAx1 = __builtin_amdgcn_ds_bpermute(addrA, (int)x1);
    int pBx0 = __builtin_amdgcn_ds_bpermute(addrB, (int)x0);
    int pBx1 = __builtin_amdgcn_ds_bpermute(addrB, (int)x1);
    int pAy0 = __builtin_amdgcn_ds_bpermute(addrA, (int)y0);
    int pAy1 = __builtin_amdgcn_ds_bpermute(addrA, (int)y1);
    int pBy0 = __builtin_amdgcn_ds_bpermute(addrB, (int)y0);
    int pBy1 = __builtin_amdgcn_ds_bpermute(addrB, (int)y1);

    union { uint32_t u[4]; short8 s; } pf;
    bool hi = quad >= 2;
    pf.u[0] = (uint32_t)(hi ? pAy0 : pAx0);
    pf.u[1] = (uint32_t)(hi ? pAy1 : pAx1);
    pf.u[2] = (uint32_t)(hi ? pBy0 : pBx0);
    pf.u[3] = (uint32_t)(hi ? pBy1 : pBx1);

    #pragma unroll
    for (int j = 0; j < 8; j++)
      o[j] = __builtin_amdgcn_mfma_f32_16x16x32_bf16(pf.s, vfr[j], o[j], 0, 0, 0);
    ol = __builtin_amdgcn_mfma_f32_16x16x32_bf16(pf.s, ones, ol, 0, 0, 0);

    kp += 4096;
    vp += 4096;
  }

  int slot = (bh * 32 + qt) * 4 + c;
  u16* pob = po + (size_t)slot * 8192;
  #pragma unroll
  for (int r = 0; r < 4; r++) {
    int qr = wave * 16 + quad * 4 + r;
    #pragma unroll
    for (int j = 0; j < 8; j++)
      pob[qr * 128 + j * 16 + lane16] = f2bf(o[j][r]);
    if (lane16 == 0) pl[slot * 64 + qr] = ol[r];
  }
}

// ---------------- reduce: VERBATIM (frozen) ----------------
__global__ __launch_bounds__(256) void reduce_kernel(const u16* __restrict__ po,
                                                     const float* __restrict__ pl,
                                                     u16* __restrict__ attn) {
  int bh = blockIdx.x >> 5, qt = blockIdx.x & 31;
  int tid = threadIdx.x;
  int nch = (2 * qt + 17) >> 4;
  int qrow = tid >> 2;
  int d0 = (tid & 3) * 32;
  float acc[32];
  #pragma unroll
  for (int i = 0; i < 32; i++) acc[i] = 0.0f;
  float l = 0.0f;
  int slot0 = (bh * 32 + qt) * 4;
  for (int c = 0; c < nch; c++) {
    int slot = slot0 + c;
    l += pl[slot * 64 + qrow];
    const short8* p = (const short8*)(po + (size_t)slot * 8192 + qrow * 128 + d0);
    #pragma unroll
    for (int v = 0; v < 4; v++) {
      short8 pk = p[v];
      #pragma unroll
      for (int e = 0; e < 8; e++) acc[v * 8 + e] += bf2f((u16)pk[e]);
    }
  }
  float inv = rcpa(l);
  int b = bh >> 2, h = bh & 3, t = qt * 64 + qrow;
  u16* orow = attn + ((size_t)(b * TSEQ + t)) * CMOD + h * HD + d0;
  #pragma unroll
  for (int v = 0; v < 4; v++) {
    short8 ov;
    #pragma unroll
    for (int e = 0; e < 8; e++) ov[e] = (short)f2bf(acc[v * 8 + e] * inv);
    *(short8*)(orow + v * 8) = ov;
  }
}

extern "C" void kernel_launch(void* const* d_in, const int* in_sizes, int n_in,
                              void* d_out, int out_size, void* d_ws, size_t ws_size,
                              hipStream_t stream) {
  const float* x     = (const float*)d_in[0];
  const float* ln1g  = (const float*)d_in[1];
  const float* ln1b  = (const float*)d_in[2];
  const float* wqkv  = (const float*)d_in[3];
  const float* wproj = (const float*)d_in[4];
  const float* ln2g  = (const float*)d_in[5];
  const float* ln2b  = (const float*)d_in[6];
  const float* wff1  = (const float*)d_in[7];
  const float* wff2  = (const float*)d_in[8];
  float* out = (float*)d_out;
  char* ws = (char*)d_ws;

  u16* wt_qkv  = (u16*)(ws);
  u16* wt_proj = (u16*)(ws + 1572864);
  u16* wt_ff1  = (u16*)(ws + 2097152);
  u16* wt_ff2  = (u16*)(ws + 4194304);
  u16* ln_buf  = (u16*)(ws + 6291456);
  u16* q_buf   = (u16*)(ws + 14680064);
  u16* k_buf   = (u16*)(ws + 23068672);
  u16* vt_buf  = (u16*)(ws + 31457280);
  u16* attn    = (u16*)(ws + 39845888);
  float* x2    = (float*)(ws + 48234496);
  u16* h1      = (u16*)(ws + 65011712);
  u16* po      = (u16*)(ws + 48234496);
  float* pl    = (float*)(ws + 81788928);

  dim3 blk(256);
  prep_kernel<<<dim3(5120), blk, 0, stream>>>(x, ln1g, ln1b, wqkv, wproj, wff1, wff2,
                                              ln_buf, wt_qkv, wt_proj, wt_ff1, wt_ff2);

  // QKV: TM=128,TN=64, grid 24x64 = 1536 blocks
  gemm_kernel<0, 128, 64, 6><<<dim3(CQKV / 64, BT / 128), blk, 0, stream>>>(
      ln_buf, wt_qkv, CMOD, nullptr, nullptr, q_buf, k_buf, vt_buf);

  // attn: 1D grid 1280 = 16 bh x 80 chunks, XCD-locality swizzle (bh = n & 15)
  attn_kernel<<<dim3(1280), blk, 0, stream>>>(q_buf, k_buf, vt_buf, po, pl);

  reduce_kernel<<<dim3(512), blk, 0, stream>>>(po, pl, attn);

  // proj: TM=128,TN=64, grid 8x64 = 512 blocks
  gemm_kernel<1, 128, 64, 4><<<dim3(CMOD / 64, BT / 128), blk, 0, stream>>>(
      attn, wt_proj, CMOD, x, x2, nullptr, nullptr, nullptr);

  ln_kernel<<<dim3(BT / 4), blk, 0, stream>>>(x2, ln2g, ln2b, ln_buf);

  // FF1: TM=128,TN=64, grid 32x64 = 2048 blocks
  gemm_kernel<2, 128, 64, 6><<<dim3(DFF / 64, BT / 128), blk, 0, stream>>>(
      ln_buf, wt_ff1, CMOD, nullptr, nullptr, h1, nullptr, nullptr);

  // FF2: TM=128,TN=64, grid 8x64 = 512 blocks
  gemm_kernel<3, 128, 64, 4><<<dim3(CMOD / 64, BT / 128), blk, 0, stream>>>(
      h1, wt_ff2, DFF, x2, out, nullptr, nullptr, nullptr);
}

// Round 10
// 272.884 us; speedup vs baseline: 1.0352x; 1.0028x over previous
//
#include <hip/hip_runtime.h>
#include <cstdint>

typedef unsigned short u16;
typedef __attribute__((ext_vector_type(8))) short short8;
typedef __attribute__((ext_vector_type(4))) float floatx4;

#define BT    8192
#define TSEQ  2048
#define NBAT  4
#define CMOD  512
#define NH    4
#define HD    128
#define DFF   2048
#define CQKV  1536

__device__ __forceinline__ u16 f2bf(float f) {
  union { float f; uint32_t u; } v; v.f = f;
  uint32_t r = v.u + 0x7FFFu + ((v.u >> 16) & 1u);
  return (u16)(r >> 16);
}
__device__ __forceinline__ float bf2f(u16 u) {
  union { uint32_t u; float f; } v; v.u = ((uint32_t)u) << 16; return v.f;
}
__device__ __forceinline__ float exp2a(float x) {
  float r; asm("v_exp_f32 %0, %1" : "=v"(r) : "v"(x)); return r;
}
__device__ __forceinline__ float rcpa(float x) {
  float r; asm("v_rcp_f32 %0, %1" : "=v"(r) : "v"(x)); return r;
}

typedef __attribute__((address_space(1))) const unsigned int ga_u32;
typedef __attribute__((address_space(3))) unsigned int ls_u32;
__device__ __forceinline__ void glds16(const u16* g, u16* l) {
  __builtin_amdgcn_global_load_lds((ga_u32*)g, (ls_u32*)l, 16, 0, 0);
}

// ---------------- fused prep: 4 weight transposes + LN1 (frozen) ----------------
__device__ __forceinline__ void tcast_body(const float* __restrict__ W, u16* __restrict__ Wt,
                                           int K, int N, int bx, int by, int tid,
                                           float (*tile)[33]) {
  int n0 = bx * 32, k0 = by * 32;
  int tx = tid & 31, ty = tid >> 5;
  #pragma unroll
  for (int r = 0; r < 32; r += 8)
    tile[r + ty][tx] = W[(size_t)(k0 + r + ty) * N + n0 + tx];
  __syncthreads();
  #pragma unroll
  for (int r = 0; r < 32; r += 8)
    Wt[(size_t)(n0 + r + ty) * K + k0 + tx] = f2bf(tile[tx][r + ty]);
}

__global__ __launch_bounds__(256) void prep_kernel(
    const float* __restrict__ x, const float* __restrict__ g, const float* __restrict__ b,
    const float* __restrict__ wqkv, const float* __restrict__ wproj,
    const float* __restrict__ wff1, const float* __restrict__ wff2,
    u16* __restrict__ ln_out, u16* __restrict__ wqkvT, u16* __restrict__ wprojT,
    u16* __restrict__ wff1T, u16* __restrict__ wff2T) {
  __shared__ float tile[32][33];
  int bid = blockIdx.x, tid = threadIdx.x;
  if (bid < 768) {
    tcast_body(wqkv, wqkvT, CMOD, CQKV, bid % 48, bid / 48, tid, tile);
  } else if (bid < 1024) {
    int id = bid - 768; tcast_body(wproj, wprojT, CMOD, CMOD, id % 16, id / 16, tid, tile);
  } else if (bid < 2048) {
    int id = bid - 1024; tcast_body(wff1, wff1T, CMOD, DFF, id % 64, id / 64, tid, tile);
  } else if (bid < 3072) {
    int id = bid - 2048; tcast_body(wff2, wff2T, DFF, CMOD, id % 16, id / 16, tid, tile);
  } else {
    int row = (bid - 3072) * 4 + (tid >> 6);
    int lane = tid & 63;
    const float4* xr = (const float4*)(x + (size_t)row * CMOD);
    float4 a = xr[lane], c = xr[lane + 64];
    float s = a.x + a.y + a.z + a.w + c.x + c.y + c.z + c.w;
    float q = a.x*a.x + a.y*a.y + a.z*a.z + a.w*a.w
            + c.x*c.x + c.y*c.y + c.z*c.z + c.w*c.w;
    #pragma unroll
    for (int o = 32; o; o >>= 1) { s += __shfl_xor(s, o); q += __shfl_xor(q, o); }
    float mu = s * (1.0f / CMOD);
    float rstd = rsqrtf(q * (1.0f / CMOD) - mu * mu + 1e-5f);
    const float4* gr = (const float4*)g;
    const float4* br = (const float4*)b;
    float4 g0 = gr[lane], g1 = gr[lane + 64], b0 = br[lane], b1 = br[lane + 64];
    u16* orow = ln_out + (size_t)row * CMOD;
    int i0 = lane * 4, i1 = (lane + 64) * 4;
    orow[i0 + 0] = f2bf((a.x - mu) * rstd * g0.x + b0.x);
    orow[i0 + 1] = f2bf((a.y - mu) * rstd * g0.y + b0.y);
    orow[i0 + 2] = f2bf((a.z - mu) * rstd * g0.z + b0.z);
    orow[i0 + 3] = f2bf((a.w - mu) * rstd * g0.w + b0.w);
    orow[i1 + 0] = f2bf((c.x - mu) * rstd * g1.x + b1.x);
    orow[i1 + 1] = f2bf((c.y - mu) * rstd * g1.y + b1.y);
    orow[i1 + 2] = f2bf((c.z - mu) * rstd * g1.z + b1.z);
    orow[i1 + 3] = f2bf((c.w - mu) * rstd * g1.w + b1.w);
  }
}

// ---------------- layernorm (standalone, for LN2; frozen) ----------------
__global__ __launch_bounds__(256) void ln_kernel(const float* __restrict__ x,
                                                 const float* __restrict__ g,
                                                 const float* __restrict__ b,
                                                 u16* __restrict__ out) {
  int row = blockIdx.x * 4 + (threadIdx.x >> 6);
  int lane = threadIdx.x & 63;
  const float4* xr = (const float4*)(x + (size_t)row * CMOD);
  float4 a = xr[lane], c = xr[lane + 64];
  float s = a.x + a.y + a.z + a.w + c.x + c.y + c.z + c.w;
  float q = a.x*a.x + a.y*a.y + a.z*a.z + a.w*a.w
          + c.x*c.x + c.y*c.y + c.z*c.z + c.w*c.w;
  #pragma unroll
  for (int o = 32; o; o >>= 1) { s += __shfl_xor(s, o); q += __shfl_xor(q, o); }
  float mu = s * (1.0f / CMOD);
  float rstd = rsqrtf(q * (1.0f / CMOD) - mu * mu + 1e-5f);
  const float4* gr = (const float4*)g;
  const float4* br = (const float4*)b;
  float4 g0 = gr[lane], g1 = gr[lane + 64], b0 = br[lane], b1 = br[lane + 64];
  u16* orow = out + (size_t)row * CMOD;
  int i0 = lane * 4, i1 = (lane + 64) * 4;
  orow[i0 + 0] = f2bf((a.x - mu) * rstd * g0.x + b0.x);
  orow[i0 + 1] = f2bf((a.y - mu) * rstd * g0.y + b0.y);
  orow[i0 + 2] = f2bf((a.z - mu) * rstd * g0.z + b0.z);
  orow[i0 + 3] = f2bf((a.w - mu) * rstd * g0.w + b0.w);
  orow[i1 + 0] = f2bf((c.x - mu) * rstd * g1.x + b1.x);
  orow[i1 + 1] = f2bf((c.y - mu) * rstd * g1.y + b1.y);
  orow[i1 + 2] = f2bf((c.z - mu) * rstd * g1.z + b1.z);
  orow[i1 + 3] = f2bf((c.w - mu) * rstd * g1.w + b1.w);
}

// ---------------- MFMA GEMM: R6 (frozen, incl. fragment-blocked EPI=0) ----------------
template <int EPI, int TM, int TN, int MINW>
__global__ __launch_bounds__(256, MINW) void gemm_kernel(
    const u16* __restrict__ A, const u16* __restrict__ Bt, int K,
    const float* __restrict__ resid, float* __restrict__ outf,
    u16* __restrict__ ob0, u16* __restrict__ ob1, u16* __restrict__ ob2) {
  constexpr int MR  = TM / 32;
  constexpr int NR  = TN / 32;
  constexpr int NAR = TM / 64;
  constexpr int NBR = TN / 64;
  __shared__ __align__(16) u16 As[2][TM * 32];
  __shared__ __align__(16) u16 Bs[2][TN * 32];
  int tid = threadIdx.x;
  int lane = tid & 63, wave = tid >> 6;
  int lane16 = lane & 15, quad = lane >> 4;
  int m0 = blockIdx.y * TM, n0 = blockIdx.x * TN;
  int wm = (wave >> 1) * (TM / 2), wn = (wave & 1) * (TN / 2);

  floatx4 acc[MR][NR];
  #pragma unroll
  for (int i = 0; i < MR; i++)
    #pragma unroll
    for (int j = 0; j < NR; j++) acc[i][j] = (floatx4)(0.0f);

  const u16* agp[NAR]; u16* alp[NAR][2];
  const u16* bgp[NBR]; u16* blp[NBR][2];
  #pragma unroll
  for (int i = 0; i < NAR; i++) {
    int s = i * 256 + tid;
    agp[i] = A + (size_t)(m0 + (s >> 2)) * K + (s & 3) * 8;
    alp[i][0] = &As[0][(i * 256 + wave * 64) * 8];
    alp[i][1] = &As[1][(i * 256 + wave * 64) * 8];
  }
  #pragma unroll
  for (int i = 0; i < NBR; i++) {
    int s = i * 256 + tid;
    bgp[i] = Bt + (size_t)(n0 + (s >> 2)) * K + (s & 3) * 8;
    blp[i][0] = &Bs[0][(i * 256 + wave * 64) * 8];
    blp[i][1] = &Bs[1][(i * 256 + wave * 64) * 8];
  }

  int nk = K >> 5;
  #pragma unroll
  for (int i = 0; i < NAR; i++) glds16(agp[i], alp[i][0]);
  #pragma unroll
  for (int i = 0; i < NBR; i++) glds16(bgp[i], blp[i][0]);

  for (int kt = 0; kt < nk; kt++) {
    __syncthreads();
    int buf = kt & 1;
    if (kt + 1 < nk) {
      int k1 = (kt + 1) * 32;
      #pragma unroll
      for (int i = 0; i < NAR; i++) glds16(agp[i] + k1, alp[i][buf ^ 1]);
      #pragma unroll
      for (int i = 0; i < NBR; i++) glds16(bgp[i] + k1, blp[i][buf ^ 1]);
    }
    short8 af[MR];
    #pragma unroll
    for (int i = 0; i < MR; i++)
      af[i] = *(const short8*)&As[buf][(wm + i * 16 + lane16) * 32 + quad * 8];
    #pragma unroll
    for (int j = 0; j < NR; j++) {
      short8 bfj = *(const short8*)&Bs[buf][(wn + j * 16 + lane16) * 32 + quad * 8];
      #pragma unroll
      for (int i = 0; i < MR; i++)
        acc[i][j] = __builtin_amdgcn_mfma_f32_16x16x32_bf16(af[i], bfj, acc[i][j], 0, 0, 0);
    }
  }

  #pragma unroll
  for (int i = 0; i < MR; i++) {
    #pragma unroll
    for (int j = 0; j < NR; j++) {
      #pragma unroll
      for (int r = 0; r < 4; r++) {
        int m = m0 + wm + i * 16 + quad * 4 + r;
        int n = n0 + wn + j * 16 + lane16;
        float v = acc[i][j][r];
        if (EPI == 0) {
          int bb = m >> 11, t = m & 2047;
          int nn = n & 511, which = n >> 9;
          int h = nn >> 7, d = nn & 127;
          size_t base = (size_t)(bb * NH + h) * 262144;
          if (which == 0) {
            int t16 = t >> 4, l16 = t & 15, cc = d >> 5, qd = (d >> 3) & 3, e = d & 7;
            ob0[base + (size_t)((t16 * 16 + cc * 4 + qd) * 128 + l16 * 8 + e)] = f2bf(v * 0.12751743f);
          } else if (which == 1) {
            int kt = t >> 5, hf = (t >> 4) & 1, l16 = t & 15, cc = d >> 5, qd = (d >> 3) & 3, e = d & 7;
            ob1[base + (size_t)((kt * 8 + hf * 4 + cc) * 512 + qd * 128 + l16 * 8 + e)] = f2bf(v);
          } else {
            int kt = t >> 5, qv = (t >> 3) & 3, e = t & 7, j2 = d >> 4, l16 = d & 15;
            ob2[base + (size_t)((kt * 8 + j2) * 512 + qv * 128 + l16 * 8 + e)] = f2bf(v);
          }
        } else if (EPI == 1) {
          size_t idx = (size_t)m * CMOD + n;
          outf[idx] = v + resid[idx];
        } else if (EPI == 2) {
          float ge = 0.5f * v * (1.0f + erff(v * 0.70710678118654752f));
          ob0[(size_t)m * DFF + n] = f2bf(ge);
        } else {
          size_t idx = (size_t)m * CMOD + n;
          outf[idx] = v + resid[idx];
        }
      }
    }
  }
}

// ---------------- flash attention: 2 K-tiles per iteration (THE ONLY CHANGE) ----------------
// R3/R6/R9 all converge to ~2900cy wall time PER WAVE-ITERATION regardless of
// structure -> the cost is one serial latency exposure per 32-k tile. This round:
// process kt and kt+1 per iteration. All 32 loads batch-issue in source order
// K-A, K-B, V-A, V-B -> compiler emits descending vmcnt ladder (QK-A@24, QK-B@16,
// PV-A@8, PV-B@0): ONE latency exposure per pair, iteration count halved.
// Pairs ascend, odd tail runs LAST -> o[j] accumulation order unchanged ->
// bit-identical output. Known risk: VGPR ~190-210 (pre-committed revert if >230
// or scratch or flat).
__global__ __launch_bounds__(256) void attn_kernel(const u16* __restrict__ qb,
                                                   const u16* __restrict__ kb,
                                                   const u16* __restrict__ vtb,
                                                   u16* __restrict__ po,
                                                   float* __restrict__ pl) {
  int tid = threadIdx.x, wave = tid >> 6, lane = tid & 63;
  int lane16 = lane & 15, quad = lane >> 4;
  int n1d = blockIdx.x;
  int bh = n1d & 15;
  int cid = 79 - (n1d >> 4);   // heavy chunks dispatch first
  int qt, c;
  if (cid < 8)       { qt = cid;                    c = 0; }
  else if (cid < 24) { qt = 8 + ((cid - 8) >> 1);   c = (cid - 8) & 1; }
  else if (cid < 48) { qt = 16 + (cid - 24) / 3;    c = (cid - 24) % 3; }
  else               { qt = 24 + ((cid - 48) >> 2); c = (cid - 48) & 3; }

  int q0w = qt * 64 + wave * 16;
  const u16* Qb = qb  + (size_t)bh * 262144;
  const u16* Kb = kb  + (size_t)bh * 262144;
  const u16* Vb = vtb + (size_t)bh * 262144;

  short8 aq[4];
  #pragma unroll
  for (int cc = 0; cc < 4; cc++)
    aq[cc] = *(const short8*)&Qb[(size_t)(((q0w >> 4) * 16 + cc * 4 + quad) * 128 + lane16 * 8)];

  int ktw   = (q0w >> 5) + 1;
  int ktblk = qt * 2 + 2;
  int kt0   = c * 16;
  int kend  = min(min(kt0 + 16, ktblk), ktw);

  floatx4 o[8];
  #pragma unroll
  for (int j = 0; j < 8; j++) o[j] = (floatx4)(0.0f);
  floatx4 ol = (floatx4)(0.0f);

  short8 ones;
  #pragma unroll
  for (int e = 0; e < 8; e++) ones[e] = (short)0x3F80;

  int addrA = (lane16 + ((quad & 1) << 5)) << 2;
  int addrB = addrA + 64;
  int q_g = q0w + lane16;

  // softmax + transpose + PV for one 32-k tile held in registers (K0_,K1_,V_)
#define ATTN_TAIL(S0, S1, V_, KT)                                                                   \
  {                                                                                                 \
    int k0b = (KT) * 32 + quad * 4;                                                                 \
    _Pragma("unroll")                                                                               \
    for (int r = 0; r < 4; r++) {                                                                   \
      float p0 = exp2a(S0[r]);                                                                      \
      float p1 = exp2a(S1[r]);                                                                      \
      if (k0b + r > q_g) p0 = 0.0f;                                                                 \
      if (k0b + r + 16 > q_g) p1 = 0.0f;                                                            \
      S0[r] = p0; S1[r] = p1;                                                                       \
    }                                                                                               \
    uint32_t x0 = __builtin_amdgcn_perm(__float_as_uint(S0[1]), __float_as_uint(S0[0]), 0x07060302u); \
    uint32_t x1 = __builtin_amdgcn_perm(__float_as_uint(S0[3]), __float_as_uint(S0[2]), 0x07060302u); \
    uint32_t y0 = __builtin_amdgcn_perm(__float_as_uint(S1[1]), __float_as_uint(S1[0]), 0x07060302u); \
    uint32_t y1 = __builtin_amdgcn_perm(__float_as_uint(S1[3]), __float_as_uint(S1[2]), 0x07060302u); \
    int pAx0 = __builtin_amdgcn_ds_bpermute(addrA, (int)x0);                                        \
    int pAx1 = __builtin_amdgcn_ds_bpermute(addrA, (int)x1);                                        \
    int pBx0 = __builtin_amdgcn_ds_bpermute(addrB, (int)x0);                                        \
    int pBx1 = __builtin_amdgcn_ds_bpermute(addrB, (int)x1);                                        \
    int pAy0 = __builtin_amdgcn_ds_bpermute(addrA, (int)y0);                                        \
    int pAy1 = __builtin_amdgcn_ds_bpermute(addrA, (int)y1);                                        \
    int pBy0 = __builtin_amdgcn_ds_bpermute(addrB, (int)y0);                                        \
    int pBy1 = __builtin_amdgcn_ds_bpermute(addrB, (int)y1);                                        \
    union { uint32_t u[4]; short8 s; } pf;                                                          \
    bool hi = quad >= 2;                                                                            \
    pf.u[0] = (uint32_t)(hi ? pAy0 : pAx0);                                                         \
    pf.u[1] = (uint32_t)(hi ? pAy1 : pAx1);                                                         \
    pf.u[2] = (uint32_t)(hi ? pBy0 : pBx0);                                                         \
    pf.u[3] = (uint32_t)(hi ? pBy1 : pBx1);                                                         \
    _Pragma("unroll")                                                                               \
    for (int j = 0; j < 8; j++)                                                                     \
      o[j] = __builtin_amdgcn_mfma_f32_16x16x32_bf16(pf.s, V_[j], o[j], 0, 0, 0);                   \
    ol = __builtin_amdgcn_mfma_f32_16x16x32_bf16(pf.s, ones, ol, 0, 0, 0);                          \
  }

  int kt = kt0;
  // ---- pair loop: 2 K-tiles per latency exposure ----
  for (; kt + 1 < kend; kt += 2) {
    const u16* kpa = Kb + (size_t)kt * 4096 + lane * 8;
    const u16* vpa = Vb + (size_t)kt * 4096 + lane * 8;
    short8 ka0[4], ka1[4], kb0[4], kb1[4], va[8], vb[8];
    #pragma unroll
    for (int cc = 0; cc < 4; cc++) {
      ka0[cc] = *(const short8*)&kpa[cc * 512];
      ka1[cc] = *(const short8*)&kpa[(4 + cc) * 512];
    }
    #pragma unroll
    for (int cc = 0; cc < 4; cc++) {
      kb0[cc] = *(const short8*)&kpa[4096 + cc * 512];
      kb1[cc] = *(const short8*)&kpa[4096 + (4 + cc) * 512];
    }
    #pragma unroll
    for (int j = 0; j < 8; j++) va[j] = *(const short8*)&vpa[j * 512];
    #pragma unroll
    for (int j = 0; j < 8; j++) vb[j] = *(const short8*)&vpa[4096 + j * 512];

    floatx4 sa0 = (floatx4)(0.0f), sa1 = (floatx4)(0.0f);
    #pragma unroll
    for (int cc = 0; cc < 4; cc++) {
      sa0 = __builtin_amdgcn_mfma_f32_16x16x32_bf16(ka0[cc], aq[cc], sa0, 0, 0, 0);
      sa1 = __builtin_amdgcn_mfma_f32_16x16x32_bf16(ka1[cc], aq[cc], sa1, 0, 0, 0);
    }
    floatx4 sb0 = (floatx4)(0.0f), sb1 = (floatx4)(0.0f);
    #pragma unroll
    for (int cc = 0; cc < 4; cc++) {
      sb0 = __builtin_amdgcn_mfma_f32_16x16x32_bf16(kb0[cc], aq[cc], sb0, 0, 0, 0);
      sb1 = __builtin_amdgcn_mfma_f32_16x16x32_bf16(kb1[cc], aq[cc], sb1, 0, 0, 0);
    }
    ATTN_TAIL(sa0, sa1, va, kt);
    ATTN_TAIL(sb0, sb1, vb, kt + 1);
  }
  // ---- odd tail (runs last -> accumulation order preserved) ----
  if (kt < kend) {
    const u16* kp = Kb + (size_t)kt * 4096 + lane * 8;
    const u16* vp = Vb + (size_t)kt * 4096 + lane * 8;
    short8 k0f[4], k1f[4], vfr[8];
    #pragma unroll
    for (int cc = 0; cc < 4; cc++) {
      k0f[cc] = *(const short8*)&kp[cc * 512];
      k1f[cc] = *(const short8*)&kp[(4 + cc) * 512];
    }
    #pragma unroll
    for (int j = 0; j < 8; j++) vfr[j] = *(const short8*)&vp[j * 512];

    floatx4 st0 = (floatx4)(0.0f), st1 = (floatx4)(0.0f);
    #pragma unroll
    for (int cc = 0; cc < 4; cc++) {
      st0 = __builtin_amdgcn_mfma_f32_16x16x32_bf16(k0f[cc], aq[cc], st0, 0, 0, 0);
      st1 = __builtin_amdgcn_mfma_f32_16x16x32_bf16(k1f[cc], aq[cc], st1, 0, 0, 0);
    }
    ATTN_TAIL(st0, st1, vfr, kt);
  }
#undef ATTN_TAIL

  int slot = (bh * 32 + qt) * 4 + c;
  u16* pob = po + (size_t)slot * 8192;
  #pragma unroll
  for (int r = 0; r < 4; r++) {
    int qr = wave * 16 + quad * 4 + r;
    #pragma unroll
    for (int j = 0; j < 8; j++)
      pob[qr * 128 + j * 16 + lane16] = f2bf(o[j][r]);
    if (lane16 == 0) pl[slot * 64 + qr] = ol[r];
  }
}

// ---------------- reduce: VERBATIM (frozen) ----------------
__global__ __launch_bounds__(256) void reduce_kernel(const u16* __restrict__ po,
                                                     const float* __restrict__ pl,
                                                     u16* __restrict__ attn) {
  int bh = blockIdx.x >> 5, qt = blockIdx.x & 31;
  int tid = threadIdx.x;
  int nch = (2 * qt + 17) >> 4;
  int qrow = tid >> 2;
  int d0 = (tid & 3) * 32;
  float acc[32];
  #pragma unroll
  for (int i = 0; i < 32; i++) acc[i] = 0.0f;
  float l = 0.0f;
  int slot0 = (bh * 32 + qt) * 4;
  for (int c = 0; c < nch; c++) {
    int slot = slot0 + c;
    l += pl[slot * 64 + qrow];
    const short8* p = (const short8*)(po + (size_t)slot * 8192 + qrow * 128 + d0);
    #pragma unroll
    for (int v = 0; v < 4; v++) {
      short8 pk = p[v];
      #pragma unroll
      for (int e = 0; e < 8; e++) acc[v * 8 + e] += bf2f((u16)pk[e]);
    }
  }
  float inv = rcpa(l);
  int b = bh >> 2, h = bh & 3, t = qt * 64 + qrow;
  u16* orow = attn + ((size_t)(b * TSEQ + t)) * CMOD + h * HD + d0;
  #pragma unroll
  for (int v = 0; v < 4; v++) {
    short8 ov;
    #pragma unroll
    for (int e = 0; e < 8; e++) ov[e] = (short)f2bf(acc[v * 8 + e] * inv);
    *(short8*)(orow + v * 8) = ov;
  }
}

extern "C" void kernel_launch(void* const* d_in, const int* in_sizes, int n_in,
                              void* d_out, int out_size, void* d_ws, size_t ws_size,
                              hipStream_t stream) {
  const float* x     = (const float*)d_in[0];
  const float* ln1g  = (const float*)d_in[1];
  const float* ln1b  = (const float*)d_in[2];
  const float* wqkv  = (const float*)d_in[3];
  const float* wproj = (const float*)d_in[4];
  const float* ln2g  = (const float*)d_in[5];
  const float* ln2b  = (const float*)d_in[6];
  const float* wff1  = (const float*)d_in[7];
  const float* wff2  = (const float*)d_in[8];
  float* out = (float*)d_out;
  char* ws = (char*)d_ws;

  u16* wt_qkv  = (u16*)(ws);
  u16* wt_proj = (u16*)(ws + 1572864);
  u16* wt_ff1  = (u16*)(ws + 2097152);
  u16* wt_ff2  = (u16*)(ws + 4194304);
  u16* ln_buf  = (u16*)(ws + 6291456);
  u16* q_buf   = (u16*)(ws + 14680064);
  u16* k_buf   = (u16*)(ws + 23068672);
  u16* vt_buf  = (u16*)(ws + 31457280);
  u16* attn    = (u16*)(ws + 39845888);
  float* x2    = (float*)(ws + 48234496);
  u16* h1      = (u16*)(ws + 65011712);
  u16* po      = (u16*)(ws + 48234496);
  float* pl    = (float*)(ws + 81788928);

  dim3 blk(256);
  prep_kernel<<<dim3(5120), blk, 0, stream>>>(x, ln1g, ln1b, wqkv, wproj, wff1, wff2,
                                              ln_buf, wt_qkv, wt_proj, wt_ff1, wt_ff2);

  // QKV: TM=128,TN=64, grid 24x64 = 1536 blocks
  gemm_kernel<0, 128, 64, 6><<<dim3(CQKV / 64, BT / 128), blk, 0, stream>>>(
      ln_buf, wt_qkv, CMOD, nullptr, nullptr, q_buf, k_buf, vt_buf);

  // attn: 1D grid 1280 = 16 bh x 80 chunks, XCD-locality swizzle (bh = n & 15)
  attn_kernel<<<dim3(1280), blk, 0, stream>>>(q_buf, k_buf, vt_buf, po, pl);

  reduce_kernel<<<dim3(512), blk, 0, stream>>>(po, pl, attn);

  // proj: TM=128,TN=64, grid 8x64 = 512 blocks
  gemm_kernel<1, 128, 64, 4><<<dim3(CMOD / 64, BT / 128), blk, 0, stream>>>(
      attn, wt_proj, CMOD, x, x2, nullptr, nullptr, nullptr);

  ln_kernel<<<dim3(BT / 4), blk, 0, stream>>>(x2, ln2g, ln2b, ln_buf);

  // FF1: TM=128,TN=64, grid 32x64 = 2048 blocks
  gemm_kernel<2, 128, 64, 6><<<dim3(DFF / 64, BT / 128), blk, 0, stream>>>(
      ln_buf, wt_ff1, CMOD, nullptr, nullptr, h1, nullptr, nullptr);

  // FF2: TM=128,TN=64, grid 8x64 = 512 blocks
  gemm_kernel<3, 128, 64, 4><<<dim3(CMOD / 64, BT / 128), blk, 0, stream>>>(
      h1, wt_ff2, DFF, x2, out, nullptr, nullptr, nullptr);
}

// Round 11
// 269.878 us; speedup vs baseline: 1.0467x; 1.0111x over previous
//
#include <hip/hip_runtime.h>
#include <cstdint>

typedef unsigned short u16;
typedef __attribute__((ext_vector_type(8))) short short8;
typedef __attribute__((ext_vector_type(4))) float floatx4;

#define BT    8192
#define TSEQ  2048
#define NBAT  4
#define CMOD  512
#define NH    4
#define HD    128
#define DFF   2048
#define CQKV  1536

__device__ __forceinline__ u16 f2bf(float f) {
  union { float f; uint32_t u; } v; v.f = f;
  uint32_t r = v.u + 0x7FFFu + ((v.u >> 16) & 1u);
  return (u16)(r >> 16);
}
__device__ __forceinline__ float bf2f(u16 u) {
  union { uint32_t u; float f; } v; v.u = ((uint32_t)u) << 16; return v.f;
}
__device__ __forceinline__ float exp2a(float x) {
  float r; asm("v_exp_f32 %0, %1" : "=v"(r) : "v"(x)); return r;
}
__device__ __forceinline__ float rcpa(float x) {
  float r; asm("v_rcp_f32 %0, %1" : "=v"(r) : "v"(x)); return r;
}

typedef __attribute__((address_space(1))) const unsigned int ga_u32;
typedef __attribute__((address_space(3))) unsigned int ls_u32;
__device__ __forceinline__ void glds16(const u16* g, u16* l) {
  __builtin_amdgcn_global_load_lds((ga_u32*)g, (ls_u32*)l, 16, 0, 0);
}

// ---------------- fused prep: 4 weight transposes + LN1 (frozen) ----------------
__device__ __forceinline__ void tcast_body(const float* __restrict__ W, u16* __restrict__ Wt,
                                           int K, int N, int bx, int by, int tid,
                                           float (*tile)[33]) {
  int n0 = bx * 32, k0 = by * 32;
  int tx = tid & 31, ty = tid >> 5;
  #pragma unroll
  for (int r = 0; r < 32; r += 8)
    tile[r + ty][tx] = W[(size_t)(k0 + r + ty) * N + n0 + tx];
  __syncthreads();
  #pragma unroll
  for (int r = 0; r < 32; r += 8)
    Wt[(size_t)(n0 + r + ty) * K + k0 + tx] = f2bf(tile[tx][r + ty]);
}

__global__ __launch_bounds__(256) void prep_kernel(
    const float* __restrict__ x, const float* __restrict__ g, const float* __restrict__ b,
    const float* __restrict__ wqkv, const float* __restrict__ wproj,
    const float* __restrict__ wff1, const float* __restrict__ wff2,
    u16* __restrict__ ln_out, u16* __restrict__ wqkvT, u16* __restrict__ wprojT,
    u16* __restrict__ wff1T, u16* __restrict__ wff2T) {
  __shared__ float tile[32][33];
  int bid = blockIdx.x, tid = threadIdx.x;
  if (bid < 768) {
    tcast_body(wqkv, wqkvT, CMOD, CQKV, bid % 48, bid / 48, tid, tile);
  } else if (bid < 1024) {
    int id = bid - 768; tcast_body(wproj, wprojT, CMOD, CMOD, id % 16, id / 16, tid, tile);
  } else if (bid < 2048) {
    int id = bid - 1024; tcast_body(wff1, wff1T, CMOD, DFF, id % 64, id / 64, tid, tile);
  } else if (bid < 3072) {
    int id = bid - 2048; tcast_body(wff2, wff2T, DFF, CMOD, id % 16, id / 16, tid, tile);
  } else {
    int row = (bid - 3072) * 4 + (tid >> 6);
    int lane = tid & 63;
    const float4* xr = (const float4*)(x + (size_t)row * CMOD);
    float4 a = xr[lane], c = xr[lane + 64];
    float s = a.x + a.y + a.z + a.w + c.x + c.y + c.z + c.w;
    float q = a.x*a.x + a.y*a.y + a.z*a.z + a.w*a.w
            + c.x*c.x + c.y*c.y + c.z*c.z + c.w*c.w;
    #pragma unroll
    for (int o = 32; o; o >>= 1) { s += __shfl_xor(s, o); q += __shfl_xor(q, o); }
    float mu = s * (1.0f / CMOD);
    float rstd = rsqrtf(q * (1.0f / CMOD) - mu * mu + 1e-5f);
    const float4* gr = (const float4*)g;
    const float4* br = (const float4*)b;
    float4 g0 = gr[lane], g1 = gr[lane + 64], b0 = br[lane], b1 = br[lane + 64];
    u16* orow = ln_out + (size_t)row * CMOD;
    int i0 = lane * 4, i1 = (lane + 64) * 4;
    orow[i0 + 0] = f2bf((a.x - mu) * rstd * g0.x + b0.x);
    orow[i0 + 1] = f2bf((a.y - mu) * rstd * g0.y + b0.y);
    orow[i0 + 2] = f2bf((a.z - mu) * rstd * g0.z + b0.z);
    orow[i0 + 3] = f2bf((a.w - mu) * rstd * g0.w + b0.w);
    orow[i1 + 0] = f2bf((c.x - mu) * rstd * g1.x + b1.x);
    orow[i1 + 1] = f2bf((c.y - mu) * rstd * g1.y + b1.y);
    orow[i1 + 2] = f2bf((c.z - mu) * rstd * g1.z + b1.z);
    orow[i1 + 3] = f2bf((c.w - mu) * rstd * g1.w + b1.w);
  }
}

// ---------------- layernorm (standalone, for LN2; frozen) ----------------
__global__ __launch_bounds__(256) void ln_kernel(const float* __restrict__ x,
                                                 const float* __restrict__ g,
                                                 const float* __restrict__ b,
                                                 u16* __restrict__ out) {
  int row = blockIdx.x * 4 + (threadIdx.x >> 6);
  int lane = threadIdx.x & 63;
  const float4* xr = (const float4*)(x + (size_t)row * CMOD);
  float4 a = xr[lane], c = xr[lane + 64];
  float s = a.x + a.y + a.z + a.w + c.x + c.y + c.z + c.w;
  float q = a.x*a.x + a.y*a.y + a.z*a.z + a.w*a.w
          + c.x*c.x + c.y*c.y + c.z*c.z + c.w*c.w;
  #pragma unroll
  for (int o = 32; o; o >>= 1) { s += __shfl_xor(s, o); q += __shfl_xor(q, o); }
  float mu = s * (1.0f / CMOD);
  float rstd = rsqrtf(q * (1.0f / CMOD) - mu * mu + 1e-5f);
  const float4* gr = (const float4*)g;
  const float4* br = (const float4*)b;
  float4 g0 = gr[lane], g1 = gr[lane + 64], b0 = br[lane], b1 = br[lane + 64];
  u16* orow = out + (size_t)row * CMOD;
  int i0 = lane * 4, i1 = (lane + 64) * 4;
  orow[i0 + 0] = f2bf((a.x - mu) * rstd * g0.x + b0.x);
  orow[i0 + 1] = f2bf((a.y - mu) * rstd * g0.y + b0.y);
  orow[i0 + 2] = f2bf((a.z - mu) * rstd * g0.z + b0.z);
  orow[i0 + 3] = f2bf((a.w - mu) * rstd * g0.w + b0.w);
  orow[i1 + 0] = f2bf((c.x - mu) * rstd * g1.x + b1.x);
  orow[i1 + 1] = f2bf((c.y - mu) * rstd * g1.y + b1.y);
  orow[i1 + 2] = f2bf((c.z - mu) * rstd * g1.z + b1.z);
  orow[i1 + 3] = f2bf((c.w - mu) * rstd * g1.w + b1.w);
}

// ---------------- MFMA GEMM: R6 (frozen, incl. fragment-blocked EPI=0) ----------------
template <int EPI, int TM, int TN, int MINW>
__global__ __launch_bounds__(256, MINW) void gemm_kernel(
    const u16* __restrict__ A, const u16* __restrict__ Bt, int K,
    const float* __restrict__ resid, float* __restrict__ outf,
    u16* __restrict__ ob0, u16* __restrict__ ob1, u16* __restrict__ ob2) {
  constexpr int MR  = TM / 32;
  constexpr int NR  = TN / 32;
  constexpr int NAR = TM / 64;
  constexpr int NBR = TN / 64;
  __shared__ __align__(16) u16 As[2][TM * 32];
  __shared__ __align__(16) u16 Bs[2][TN * 32];
  int tid = threadIdx.x;
  int lane = tid & 63, wave = tid >> 6;
  int lane16 = lane & 15, quad = lane >> 4;
  int m0 = blockIdx.y * TM, n0 = blockIdx.x * TN;
  int wm = (wave >> 1) * (TM / 2), wn = (wave & 1) * (TN / 2);

  floatx4 acc[MR][NR];
  #pragma unroll
  for (int i = 0; i < MR; i++)
    #pragma unroll
    for (int j = 0; j < NR; j++) acc[i][j] = (floatx4)(0.0f);

  const u16* agp[NAR]; u16* alp[NAR][2];
  const u16* bgp[NBR]; u16* blp[NBR][2];
  #pragma unroll
  for (int i = 0; i < NAR; i++) {
    int s = i * 256 + tid;
    agp[i] = A + (size_t)(m0 + (s >> 2)) * K + (s & 3) * 8;
    alp[i][0] = &As[0][(i * 256 + wave * 64) * 8];
    alp[i][1] = &As[1][(i * 256 + wave * 64) * 8];
  }
  #pragma unroll
  for (int i = 0; i < NBR; i++) {
    int s = i * 256 + tid;
    bgp[i] = Bt + (size_t)(n0 + (s >> 2)) * K + (s & 3) * 8;
    blp[i][0] = &Bs[0][(i * 256 + wave * 64) * 8];
    blp[i][1] = &Bs[1][(i * 256 + wave * 64) * 8];
  }

  int nk = K >> 5;
  #pragma unroll
  for (int i = 0; i < NAR; i++) glds16(agp[i], alp[i][0]);
  #pragma unroll
  for (int i = 0; i < NBR; i++) glds16(bgp[i], blp[i][0]);

  for (int kt = 0; kt < nk; kt++) {
    __syncthreads();
    int buf = kt & 1;
    if (kt + 1 < nk) {
      int k1 = (kt + 1) * 32;
      #pragma unroll
      for (int i = 0; i < NAR; i++) glds16(agp[i] + k1, alp[i][buf ^ 1]);
      #pragma unroll
      for (int i = 0; i < NBR; i++) glds16(bgp[i] + k1, blp[i][buf ^ 1]);
    }
    short8 af[MR];
    #pragma unroll
    for (int i = 0; i < MR; i++)
      af[i] = *(const short8*)&As[buf][(wm + i * 16 + lane16) * 32 + quad * 8];
    #pragma unroll
    for (int j = 0; j < NR; j++) {
      short8 bfj = *(const short8*)&Bs[buf][(wn + j * 16 + lane16) * 32 + quad * 8];
      #pragma unroll
      for (int i = 0; i < MR; i++)
        acc[i][j] = __builtin_amdgcn_mfma_f32_16x16x32_bf16(af[i], bfj, acc[i][j], 0, 0, 0);
    }
  }

  #pragma unroll
  for (int i = 0; i < MR; i++) {
    #pragma unroll
    for (int j = 0; j < NR; j++) {
      #pragma unroll
      for (int r = 0; r < 4; r++) {
        int m = m0 + wm + i * 16 + quad * 4 + r;
        int n = n0 + wn + j * 16 + lane16;
        float v = acc[i][j][r];
        if (EPI == 0) {
          int bb = m >> 11, t = m & 2047;
          int nn = n & 511, which = n >> 9;
          int h = nn >> 7, d = nn & 127;
          size_t base = (size_t)(bb * NH + h) * 262144;
          if (which == 0) {
            int t16 = t >> 4, l16 = t & 15, cc = d >> 5, qd = (d >> 3) & 3, e = d & 7;
            ob0[base + (size_t)((t16 * 16 + cc * 4 + qd) * 128 + l16 * 8 + e)] = f2bf(v * 0.12751743f);
          } else if (which == 1) {
            int kt = t >> 5, hf = (t >> 4) & 1, l16 = t & 15, cc = d >> 5, qd = (d >> 3) & 3, e = d & 7;
            ob1[base + (size_t)((kt * 8 + hf * 4 + cc) * 512 + qd * 128 + l16 * 8 + e)] = f2bf(v);
          } else {
            int kt = t >> 5, qv = (t >> 3) & 3, e = t & 7, j2 = d >> 4, l16 = d & 15;
            ob2[base + (size_t)((kt * 8 + j2) * 512 + qv * 128 + l16 * 8 + e)] = f2bf(v);
          }
        } else if (EPI == 1) {
          size_t idx = (size_t)m * CMOD + n;
          outf[idx] = v + resid[idx];
        } else if (EPI == 2) {
          float ge = 0.5f * v * (1.0f + erff(v * 0.70710678118654752f));
          ob0[(size_t)m * DFF + n] = f2bf(ge);
        } else {
          size_t idx = (size_t)m * CMOD + n;
          outf[idx] = v + resid[idx];
        }
      }
    }
  }
}

// ---------------- flash attention: 8-tile chunks -> 2304 blocks (THE ONLY CHANGE) ----------------
// R3..R10: three different structures all ~2900cy/wave-iter; occupancy pinned at
// 15-20% by WORK decomposition (5120 waves = 20/CU; VGPR=80 would allow 24/CU).
// Latency-bound at 1/4 possible TLP -> halve chunk to 8 k-tiles: 144 chunks/bh,
// 2304 blocks, 9216 waves = 36/CU of work, ~24 resident (75% occ). Inner loop
// byte-identical to R10 (pair + tail). po grows to 2304 slots (36.9MB, fits ws);
// reduce reads g=qt/4+1 chunks. Chunk boundaries move -> partial-sum rounding
// points move -> NOT bit-identical (predict absmax <= ~0.06 vs thr 0.104).
__global__ __launch_bounds__(256) void attn_kernel(const u16* __restrict__ qb,
                                                   const u16* __restrict__ kb,
                                                   const u16* __restrict__ vtb,
                                                   u16* __restrict__ po,
                                                   float* __restrict__ pl) {
  int tid = threadIdx.x, wave = tid >> 6, lane = tid & 63;
  int lane16 = lane & 15, quad = lane >> 4;
  int n1d = blockIdx.x;
  int bh = n1d & 15;
  int idx = 143 - (n1d >> 4);   // heavy (large qt) chunks dispatch first
  // decode idx -> (qt, c): group g = qt/4+1 has 4 qt's, g chunks each;
  // group g occupies idx range [2g(g-1), 2g(g+1))
  int g = 1;
  #pragma unroll
  for (int t = 2; t <= 8; t++) if (idx >= 2 * t * (t - 1)) g = t;
  int rem = idx - 2 * g * (g - 1);
  int qi = rem / g;
  int c  = rem - qi * g;
  int qt = ((g - 1) << 2) + qi;

  int q0w = qt * 64 + wave * 16;
  const u16* Qb = qb  + (size_t)bh * 262144;
  const u16* Kb = kb  + (size_t)bh * 262144;
  const u16* Vb = vtb + (size_t)bh * 262144;

  short8 aq[4];
  #pragma unroll
  for (int cc = 0; cc < 4; cc++)
    aq[cc] = *(const short8*)&Qb[(size_t)(((q0w >> 4) * 16 + cc * 4 + quad) * 128 + lane16 * 8)];

  int ktw   = (q0w >> 5) + 1;
  int ktblk = qt * 2 + 2;
  int kt0   = c * 8;
  int kend  = min(min(kt0 + 8, ktblk), ktw);

  floatx4 o[8];
  #pragma unroll
  for (int j = 0; j < 8; j++) o[j] = (floatx4)(0.0f);
  floatx4 ol = (floatx4)(0.0f);

  short8 ones;
  #pragma unroll
  for (int e = 0; e < 8; e++) ones[e] = (short)0x3F80;

  int addrA = (lane16 + ((quad & 1) << 5)) << 2;
  int addrB = addrA + 64;
  int q_g = q0w + lane16;

#define ATTN_TAIL(S0, S1, V_, KT)                                                                   \
  {                                                                                                 \
    int k0b = (KT) * 32 + quad * 4;                                                                 \
    _Pragma("unroll")                                                                               \
    for (int r = 0; r < 4; r++) {                                                                   \
      float p0 = exp2a(S0[r]);                                                                      \
      float p1 = exp2a(S1[r]);                                                                      \
      if (k0b + r > q_g) p0 = 0.0f;                                                                 \
      if (k0b + r + 16 > q_g) p1 = 0.0f;                                                            \
      S0[r] = p0; S1[r] = p1;                                                                       \
    }                                                                                               \
    uint32_t x0 = __builtin_amdgcn_perm(__float_as_uint(S0[1]), __float_as_uint(S0[0]), 0x07060302u); \
    uint32_t x1 = __builtin_amdgcn_perm(__float_as_uint(S0[3]), __float_as_uint(S0[2]), 0x07060302u); \
    uint32_t y0 = __builtin_amdgcn_perm(__float_as_uint(S1[1]), __float_as_uint(S1[0]), 0x07060302u); \
    uint32_t y1 = __builtin_amdgcn_perm(__float_as_uint(S1[3]), __float_as_uint(S1[2]), 0x07060302u); \
    int pAx0 = __builtin_amdgcn_ds_bpermute(addrA, (int)x0);                                        \
    int pAx1 = __builtin_amdgcn_ds_bpermute(addrA, (int)x1);                                        \
    int pBx0 = __builtin_amdgcn_ds_bpermute(addrB, (int)x0);                                        \
    int pBx1 = __builtin_amdgcn_ds_bpermute(addrB, (int)x1);                                        \
    int pAy0 = __builtin_amdgcn_ds_bpermute(addrA, (int)y0);                                        \
    int pAy1 = __builtin_amdgcn_ds_bpermute(addrA, (int)y1);                                        \
    int pBy0 = __builtin_amdgcn_ds_bpermute(addrB, (int)y0);                                        \
    int pBy1 = __builtin_amdgcn_ds_bpermute(addrB, (int)y1);                                        \
    union { uint32_t u[4]; short8 s; } pf;                                                          \
    bool hi = quad >= 2;                                                                            \
    pf.u[0] = (uint32_t)(hi ? pAy0 : pAx0);                                                         \
    pf.u[1] = (uint32_t)(hi ? pAy1 : pAx1);                                                         \
    pf.u[2] = (uint32_t)(hi ? pBy0 : pBx0);                                                         \
    pf.u[3] = (uint32_t)(hi ? pBy1 : pBx1);                                                         \
    _Pragma("unroll")                                                                               \
    for (int j = 0; j < 8; j++)                                                                     \
      o[j] = __builtin_amdgcn_mfma_f32_16x16x32_bf16(pf.s, V_[j], o[j], 0, 0, 0);                   \
    ol = __builtin_amdgcn_mfma_f32_16x16x32_bf16(pf.s, ones, ol, 0, 0, 0);                          \
  }

  int kt = kt0;
  for (; kt + 1 < kend; kt += 2) {
    const u16* kpa = Kb + (size_t)kt * 4096 + lane * 8;
    const u16* vpa = Vb + (size_t)kt * 4096 + lane * 8;
    short8 ka0[4], ka1[4], kb0[4], kb1[4], va[8], vb[8];
    #pragma unroll
    for (int cc = 0; cc < 4; cc++) {
      ka0[cc] = *(const short8*)&kpa[cc * 512];
      ka1[cc] = *(const short8*)&kpa[(4 + cc) * 512];
    }
    #pragma unroll
    for (int cc = 0; cc < 4; cc++) {
      kb0[cc] = *(const short8*)&kpa[4096 + cc * 512];
      kb1[cc] = *(const short8*)&kpa[4096 + (4 + cc) * 512];
    }
    #pragma unroll
    for (int j = 0; j < 8; j++) va[j] = *(const short8*)&vpa[j * 512];
    #pragma unroll
    for (int j = 0; j < 8; j++) vb[j] = *(const short8*)&vpa[4096 + j * 512];

    floatx4 sa0 = (floatx4)(0.0f), sa1 = (floatx4)(0.0f);
    #pragma unroll
    for (int cc = 0; cc < 4; cc++) {
      sa0 = __builtin_amdgcn_mfma_f32_16x16x32_bf16(ka0[cc], aq[cc], sa0, 0, 0, 0);
      sa1 = __builtin_amdgcn_mfma_f32_16x16x32_bf16(ka1[cc], aq[cc], sa1, 0, 0, 0);
    }
    floatx4 sb0 = (floatx4)(0.0f), sb1 = (floatx4)(0.0f);
    #pragma unroll
    for (int cc = 0; cc < 4; cc++) {
      sb0 = __builtin_amdgcn_mfma_f32_16x16x32_bf16(kb0[cc], aq[cc], sb0, 0, 0, 0);
      sb1 = __builtin_amdgcn_mfma_f32_16x16x32_bf16(kb1[cc], aq[cc], sb1, 0, 0, 0);
    }
    ATTN_TAIL(sa0, sa1, va, kt);
    ATTN_TAIL(sb0, sb1, vb, kt + 1);
  }
  if (kt < kend) {
    const u16* kp = Kb + (size_t)kt * 4096 + lane * 8;
    const u16* vp = Vb + (size_t)kt * 4096 + lane * 8;
    short8 k0f[4], k1f[4], vfr[8];
    #pragma unroll
    for (int cc = 0; cc < 4; cc++) {
      k0f[cc] = *(const short8*)&kp[cc * 512];
      k1f[cc] = *(const short8*)&kp[(4 + cc) * 512];
    }
    #pragma unroll
    for (int j = 0; j < 8; j++) vfr[j] = *(const short8*)&vp[j * 512];

    floatx4 st0 = (floatx4)(0.0f), st1 = (floatx4)(0.0f);
    #pragma unroll
    for (int cc = 0; cc < 4; cc++) {
      st0 = __builtin_amdgcn_mfma_f32_16x16x32_bf16(k0f[cc], aq[cc], st0, 0, 0, 0);
      st1 = __builtin_amdgcn_mfma_f32_16x16x32_bf16(k1f[cc], aq[cc], st1, 0, 0, 0);
    }
    ATTN_TAIL(st0, st1, vfr, kt);
  }
#undef ATTN_TAIL

  // slot = bh*144 + prefix(qt) + c, prefix = 2g(g-1) + qi*g
  int slot = bh * 144 + 2 * g * (g - 1) + qi * g + c;
  u16* pob = po + (size_t)slot * 8192;
  #pragma unroll
  for (int r = 0; r < 4; r++) {
    int qr = wave * 16 + quad * 4 + r;
    #pragma unroll
    for (int j = 0; j < 8; j++)
      pob[qr * 128 + j * 16 + lane16] = f2bf(o[j][r]);
    if (lane16 == 0) pl[slot * 64 + qr] = ol[r];
  }
}

// ---------------- reduce: updated slot mapping for 8-tile chunks ----------------
__global__ __launch_bounds__(256) void reduce_kernel(const u16* __restrict__ po,
                                                     const float* __restrict__ pl,
                                                     u16* __restrict__ attn) {
  int bh = blockIdx.x >> 5, qt = blockIdx.x & 31;
  int tid = threadIdx.x;
  int g = (qt >> 2) + 1;                       // nch for this qt
  int slot0 = bh * 144 + 2 * g * (g - 1) + (qt & 3) * g;
  int qrow = tid >> 2;
  int d0 = (tid & 3) * 32;
  float acc[32];
  #pragma unroll
  for (int i = 0; i < 32; i++) acc[i] = 0.0f;
  float l = 0.0f;
  for (int c = 0; c < g; c++) {
    int slot = slot0 + c;
    l += pl[slot * 64 + qrow];
    const short8* p = (const short8*)(po + (size_t)slot * 8192 + qrow * 128 + d0);
    #pragma unroll
    for (int v = 0; v < 4; v++) {
      short8 pk = p[v];
      #pragma unroll
      for (int e = 0; e < 8; e++) acc[v * 8 + e] += bf2f((u16)pk[e]);
    }
  }
  float inv = rcpa(l);
  int b = bh >> 2, h = bh & 3, t = qt * 64 + qrow;
  u16* orow = attn + ((size_t)(b * TSEQ + t)) * CMOD + h * HD + d0;
  #pragma unroll
  for (int v = 0; v < 4; v++) {
    short8 ov;
    #pragma unroll
    for (int e = 0; e < 8; e++) ov[e] = (short)f2bf(acc[v * 8 + e] * inv);
    *(short8*)(orow + v * 8) = ov;
  }
}

extern "C" void kernel_launch(void* const* d_in, const int* in_sizes, int n_in,
                              void* d_out, int out_size, void* d_ws, size_t ws_size,
                              hipStream_t stream) {
  const float* x     = (const float*)d_in[0];
  const float* ln1g  = (const float*)d_in[1];
  const float* ln1b  = (const float*)d_in[2];
  const float* wqkv  = (const float*)d_in[3];
  const float* wproj = (const float*)d_in[4];
  const float* ln2g  = (const float*)d_in[5];
  const float* ln2b  = (const float*)d_in[6];
  const float* wff1  = (const float*)d_in[7];
  const float* wff2  = (const float*)d_in[8];
  float* out = (float*)d_out;
  char* ws = (char*)d_ws;

  u16* wt_qkv  = (u16*)(ws);
  u16* wt_proj = (u16*)(ws + 1572864);
  u16* wt_ff1  = (u16*)(ws + 2097152);
  u16* wt_ff2  = (u16*)(ws + 4194304);
  u16* ln_buf  = (u16*)(ws + 6291456);
  u16* q_buf   = (u16*)(ws + 14680064);
  u16* k_buf   = (u16*)(ws + 23068672);
  u16* vt_buf  = (u16*)(ws + 31457280);
  u16* attn    = (u16*)(ws + 39845888);
  float* x2    = (float*)(ws + 48234496);
  u16* h1      = (u16*)(ws + 65011712);
  // po: 2304 slots x 16KB = 37,748,736 B (overlaps x2/h1 region; stream-ordered safe:
  // po/pl dead after reduce, x2 written by proj after, h1 by FF1 after)
  u16* po      = (u16*)(ws + 48234496);
  float* pl    = (float*)(ws + 85983232);   // 48234496 + 37748736

  dim3 blk(256);
  prep_kernel<<<dim3(5120), blk, 0, stream>>>(x, ln1g, ln1b, wqkv, wproj, wff1, wff2,
                                              ln_buf, wt_qkv, wt_proj, wt_ff1, wt_ff2);

  // QKV: TM=128,TN=64, grid 24x64 = 1536 blocks
  gemm_kernel<0, 128, 64, 6><<<dim3(CQKV / 64, BT / 128), blk, 0, stream>>>(
      ln_buf, wt_qkv, CMOD, nullptr, nullptr, q_buf, k_buf, vt_buf);

  // attn: 1D grid 2304 = 16 bh x 144 chunks (8 k-tiles each), XCD swizzle (bh = n & 15)
  attn_kernel<<<dim3(2304), blk, 0, stream>>>(q_buf, k_buf, vt_buf, po, pl);

  reduce_kernel<<<dim3(512), blk, 0, stream>>>(po, pl, attn);

  // proj: TM=128,TN=64, grid 8x64 = 512 blocks
  gemm_kernel<1, 128, 64, 4><<<dim3(CMOD / 64, BT / 128), blk, 0, stream>>>(
      attn, wt_proj, CMOD, x, x2, nullptr, nullptr, nullptr);

  ln_kernel<<<dim3(BT / 4), blk, 0, stream>>>(x2, ln2g, ln2b, ln_buf);

  // FF1: TM=128,TN=64, grid 32x64 = 2048 blocks
  gemm_kernel<2, 128, 64, 6><<<dim3(DFF / 64, BT / 128), blk, 0, stream>>>(
      ln_buf, wt_ff1, CMOD, nullptr, nullptr, h1, nullptr, nullptr);

  // FF2: TM=128,TN=64, grid 8x64 = 512 blocks
  gemm_kernel<3, 128, 64, 4><<<dim3(CMOD / 64, BT / 128), blk, 0, stream>>>(
      h1, wt_ff2, DFF, x2, out, nullptr, nullptr, nullptr);
}

// Round 12
// 265.005 us; speedup vs baseline: 1.0660x; 1.0184x over previous
//
#include <hip/hip_runtime.h>
#include <cstdint>

typedef unsigned short u16;
typedef __attribute__((ext_vector_type(8))) short short8;
typedef __attribute__((ext_vector_type(4))) float floatx4;

#define BT    8192
#define TSEQ  2048
#define NBAT  4
#define CMOD  512
#define NH    4
#define HD    128
#define DFF   2048
#define CQKV  1536

__device__ __forceinline__ u16 f2bf(float f) {
  union { float f; uint32_t u; } v; v.f = f;
  uint32_t r = v.u + 0x7FFFu + ((v.u >> 16) & 1u);
  return (u16)(r >> 16);
}
__device__ __forceinline__ float bf2f(u16 u) {
  union { uint32_t u; float f; } v; v.u = ((uint32_t)u) << 16; return v.f;
}
__device__ __forceinline__ float exp2a(float x) {
  float r; asm("v_exp_f32 %0, %1" : "=v"(r) : "v"(x)); return r;
}
__device__ __forceinline__ float rcpa(float x) {
  float r; asm("v_rcp_f32 %0, %1" : "=v"(r) : "v"(x)); return r;
}

typedef __attribute__((address_space(1))) const unsigned int ga_u32;
typedef __attribute__((address_space(3))) unsigned int ls_u32;
__device__ __forceinline__ void glds16(const u16* g, u16* l) {
  __builtin_amdgcn_global_load_lds((ga_u32*)g, (ls_u32*)l, 16, 0, 0);
}

// ---------------- fused prep: 4 weight transposes + LN1 (frozen) ----------------
__device__ __forceinline__ void tcast_body(const float* __restrict__ W, u16* __restrict__ Wt,
                                           int K, int N, int bx, int by, int tid,
                                           float (*tile)[33]) {
  int n0 = bx * 32, k0 = by * 32;
  int tx = tid & 31, ty = tid >> 5;
  #pragma unroll
  for (int r = 0; r < 32; r += 8)
    tile[r + ty][tx] = W[(size_t)(k0 + r + ty) * N + n0 + tx];
  __syncthreads();
  #pragma unroll
  for (int r = 0; r < 32; r += 8)
    Wt[(size_t)(n0 + r + ty) * K + k0 + tx] = f2bf(tile[tx][r + ty]);
}

__global__ __launch_bounds__(256) void prep_kernel(
    const float* __restrict__ x, const float* __restrict__ g, const float* __restrict__ b,
    const float* __restrict__ wqkv, const float* __restrict__ wproj,
    const float* __restrict__ wff1, const float* __restrict__ wff2,
    u16* __restrict__ ln_out, u16* __restrict__ wqkvT, u16* __restrict__ wprojT,
    u16* __restrict__ wff1T, u16* __restrict__ wff2T) {
  __shared__ float tile[32][33];
  int bid = blockIdx.x, tid = threadIdx.x;
  if (bid < 768) {
    tcast_body(wqkv, wqkvT, CMOD, CQKV, bid % 48, bid / 48, tid, tile);
  } else if (bid < 1024) {
    int id = bid - 768; tcast_body(wproj, wprojT, CMOD, CMOD, id % 16, id / 16, tid, tile);
  } else if (bid < 2048) {
    int id = bid - 1024; tcast_body(wff1, wff1T, CMOD, DFF, id % 64, id / 64, tid, tile);
  } else if (bid < 3072) {
    int id = bid - 2048; tcast_body(wff2, wff2T, DFF, CMOD, id % 16, id / 16, tid, tile);
  } else {
    int row = (bid - 3072) * 4 + (tid >> 6);
    int lane = tid & 63;
    const float4* xr = (const float4*)(x + (size_t)row * CMOD);
    float4 a = xr[lane], c = xr[lane + 64];
    float s = a.x + a.y + a.z + a.w + c.x + c.y + c.z + c.w;
    float q = a.x*a.x + a.y*a.y + a.z*a.z + a.w*a.w
            + c.x*c.x + c.y*c.y + c.z*c.z + c.w*c.w;
    #pragma unroll
    for (int o = 32; o; o >>= 1) { s += __shfl_xor(s, o); q += __shfl_xor(q, o); }
    float mu = s * (1.0f / CMOD);
    float rstd = rsqrtf(q * (1.0f / CMOD) - mu * mu + 1e-5f);
    const float4* gr = (const float4*)g;
    const float4* br = (const float4*)b;
    float4 g0 = gr[lane], g1 = gr[lane + 64], b0 = br[lane], b1 = br[lane + 64];
    u16* orow = ln_out + (size_t)row * CMOD;
    int i0 = lane * 4, i1 = (lane + 64) * 4;
    orow[i0 + 0] = f2bf((a.x - mu) * rstd * g0.x + b0.x);
    orow[i0 + 1] = f2bf((a.y - mu) * rstd * g0.y + b0.y);
    orow[i0 + 2] = f2bf((a.z - mu) * rstd * g0.z + b0.z);
    orow[i0 + 3] = f2bf((a.w - mu) * rstd * g0.w + b0.w);
    orow[i1 + 0] = f2bf((c.x - mu) * rstd * g1.x + b1.x);
    orow[i1 + 1] = f2bf((c.y - mu) * rstd * g1.y + b1.y);
    orow[i1 + 2] = f2bf((c.z - mu) * rstd * g1.z + b1.z);
    orow[i1 + 3] = f2bf((c.w - mu) * rstd * g1.w + b1.w);
  }
}

// ---------------- layernorm (standalone, for LN2; frozen) ----------------
__global__ __launch_bounds__(256) void ln_kernel(const float* __restrict__ x,
                                                 const float* __restrict__ g,
                                                 const float* __restrict__ b,
                                                 u16* __restrict__ out) {
  int row = blockIdx.x * 4 + (threadIdx.x >> 6);
  int lane = threadIdx.x & 63;
  const float4* xr = (const float4*)(x + (size_t)row * CMOD);
  float4 a = xr[lane], c = xr[lane + 64];
  float s = a.x + a.y + a.z + a.w + c.x + c.y + c.z + c.w;
  float q = a.x*a.x + a.y*a.y + a.z*a.z + a.w*a.w
          + c.x*c.x + c.y*c.y + c.z*c.z + c.w*c.w;
  #pragma unroll
  for (int o = 32; o; o >>= 1) { s += __shfl_xor(s, o); q += __shfl_xor(q, o); }
  float mu = s * (1.0f / CMOD);
  float rstd = rsqrtf(q * (1.0f / CMOD) - mu * mu + 1e-5f);
  const float4* gr = (const float4*)g;
  const float4* br = (const float4*)b;
  float4 g0 = gr[lane], g1 = gr[lane + 64], b0 = br[lane], b1 = br[lane + 64];
  u16* orow = out + (size_t)row * CMOD;
  int i0 = lane * 4, i1 = (lane + 64) * 4;
  orow[i0 + 0] = f2bf((a.x - mu) * rstd * g0.x + b0.x);
  orow[i0 + 1] = f2bf((a.y - mu) * rstd * g0.y + b0.y);
  orow[i0 + 2] = f2bf((a.z - mu) * rstd * g0.z + b0.z);
  orow[i0 + 3] = f2bf((a.w - mu) * rstd * g0.w + b0.w);
  orow[i1 + 0] = f2bf((c.x - mu) * rstd * g1.x + b1.x);
  orow[i1 + 1] = f2bf((c.y - mu) * rstd * g1.y + b1.y);
  orow[i1 + 2] = f2bf((c.z - mu) * rstd * g1.z + b1.z);
  orow[i1 + 3] = f2bf((c.w - mu) * rstd * g1.w + b1.w);
}

// ---------------- MFMA GEMM: R6 (frozen, incl. fragment-blocked EPI=0) ----------------
template <int EPI, int TM, int TN, int MINW>
__global__ __launch_bounds__(256, MINW) void gemm_kernel(
    const u16* __restrict__ A, const u16* __restrict__ Bt, int K,
    const float* __restrict__ resid, float* __restrict__ outf,
    u16* __restrict__ ob0, u16* __restrict__ ob1, u16* __restrict__ ob2) {
  constexpr int MR  = TM / 32;
  constexpr int NR  = TN / 32;
  constexpr int NAR = TM / 64;
  constexpr int NBR = TN / 64;
  __shared__ __align__(16) u16 As[2][TM * 32];
  __shared__ __align__(16) u16 Bs[2][TN * 32];
  int tid = threadIdx.x;
  int lane = tid & 63, wave = tid >> 6;
  int lane16 = lane & 15, quad = lane >> 4;
  int m0 = blockIdx.y * TM, n0 = blockIdx.x * TN;
  int wm = (wave >> 1) * (TM / 2), wn = (wave & 1) * (TN / 2);

  floatx4 acc[MR][NR];
  #pragma unroll
  for (int i = 0; i < MR; i++)
    #pragma unroll
    for (int j = 0; j < NR; j++) acc[i][j] = (floatx4)(0.0f);

  const u16* agp[NAR]; u16* alp[NAR][2];
  const u16* bgp[NBR]; u16* blp[NBR][2];
  #pragma unroll
  for (int i = 0; i < NAR; i++) {
    int s = i * 256 + tid;
    agp[i] = A + (size_t)(m0 + (s >> 2)) * K + (s & 3) * 8;
    alp[i][0] = &As[0][(i * 256 + wave * 64) * 8];
    alp[i][1] = &As[1][(i * 256 + wave * 64) * 8];
  }
  #pragma unroll
  for (int i = 0; i < NBR; i++) {
    int s = i * 256 + tid;
    bgp[i] = Bt + (size_t)(n0 + (s >> 2)) * K + (s & 3) * 8;
    blp[i][0] = &Bs[0][(i * 256 + wave * 64) * 8];
    blp[i][1] = &Bs[1][(i * 256 + wave * 64) * 8];
  }

  int nk = K >> 5;
  #pragma unroll
  for (int i = 0; i < NAR; i++) glds16(agp[i], alp[i][0]);
  #pragma unroll
  for (int i = 0; i < NBR; i++) glds16(bgp[i], blp[i][0]);

  for (int kt = 0; kt < nk; kt++) {
    __syncthreads();
    int buf = kt & 1;
    if (kt + 1 < nk) {
      int k1 = (kt + 1) * 32;
      #pragma unroll
      for (int i = 0; i < NAR; i++) glds16(agp[i] + k1, alp[i][buf ^ 1]);
      #pragma unroll
      for (int i = 0; i < NBR; i++) glds16(bgp[i] + k1, blp[i][buf ^ 1]);
    }
    short8 af[MR];
    #pragma unroll
    for (int i = 0; i < MR; i++)
      af[i] = *(const short8*)&As[buf][(wm + i * 16 + lane16) * 32 + quad * 8];
    #pragma unroll
    for (int j = 0; j < NR; j++) {
      short8 bfj = *(const short8*)&Bs[buf][(wn + j * 16 + lane16) * 32 + quad * 8];
      #pragma unroll
      for (int i = 0; i < MR; i++)
        acc[i][j] = __builtin_amdgcn_mfma_f32_16x16x32_bf16(af[i], bfj, acc[i][j], 0, 0, 0);
    }
  }

  #pragma unroll
  for (int i = 0; i < MR; i++) {
    #pragma unroll
    for (int j = 0; j < NR; j++) {
      #pragma unroll
      for (int r = 0; r < 4; r++) {
        int m = m0 + wm + i * 16 + quad * 4 + r;
        int n = n0 + wn + j * 16 + lane16;
        float v = acc[i][j][r];
        if (EPI == 0) {
          int bb = m >> 11, t = m & 2047;
          int nn = n & 511, which = n >> 9;
          int h = nn >> 7, d = nn & 127;
          size_t base = (size_t)(bb * NH + h) * 262144;
          if (which == 0) {
            int t16 = t >> 4, l16 = t & 15, cc = d >> 5, qd = (d >> 3) & 3, e = d & 7;
            ob0[base + (size_t)((t16 * 16 + cc * 4 + qd) * 128 + l16 * 8 + e)] = f2bf(v * 0.12751743f);
          } else if (which == 1) {
            int kt = t >> 5, hf = (t >> 4) & 1, l16 = t & 15, cc = d >> 5, qd = (d >> 3) & 3, e = d & 7;
            ob1[base + (size_t)((kt * 8 + hf * 4 + cc) * 512 + qd * 128 + l16 * 8 + e)] = f2bf(v);
          } else {
            int kt = t >> 5, qv = (t >> 3) & 3, e = t & 7, j2 = d >> 4, l16 = d & 15;
            ob2[base + (size_t)((kt * 8 + j2) * 512 + qv * 128 + l16 * 8 + e)] = f2bf(v);
          }
        } else if (EPI == 1) {
          size_t idx = (size_t)m * CMOD + n;
          outf[idx] = v + resid[idx];
        } else if (EPI == 2) {
          float ge = 0.5f * v * (1.0f + erff(v * 0.70710678118654752f));
          ob0[(size_t)m * DFF + n] = f2bf(ge);
        } else {
          size_t idx = (size_t)m * CMOD + n;
          outf[idx] = v + resid[idx];
        }
      }
    }
  }
}

// ---------------- flash attention: 32 q-rows/wave, K/V reused 2x (THE ONLY CHANGE) ----------------
// R11 arithmetic: 16KB fragment traffic per wave-iter saturates the per-CU vector-
// memory pipe (~effective 1.7 blocks/CU no matter the wave-slot headroom). Fix:
// each wave now computes TWO Q sub-tiles (32 rows) from the SAME K/V fragments ->
// bytes per unit work HALVED; wave-iters halved (33.8K). Block = 128 thr (2 waves
// x 32 rows = one qt). Chunking/slots/reduce unchanged. q0w = 0 mod 32 so
// ktw = (q0w>>5)+1 covers both sub-tiles with the identical k-tile set as R11;
// per-row MFMA/exp order unchanged -> bit-identical output (absmax 0.03125).
// Tripwire: VGPR > 210 or scratch -> revert to R11 attn.
__global__ __launch_bounds__(128) void attn_kernel(const u16* __restrict__ qb,
                                                   const u16* __restrict__ kb,
                                                   const u16* __restrict__ vtb,
                                                   u16* __restrict__ po,
                                                   float* __restrict__ pl) {
  int tid = threadIdx.x, wave = tid >> 6, lane = tid & 63;
  int lane16 = lane & 15, quad = lane >> 4;
  int n1d = blockIdx.x;
  int bh = n1d & 15;
  int idx = 143 - (n1d >> 4);   // heavy (large qt) chunks dispatch first
  int g = 1;
  #pragma unroll
  for (int t = 2; t <= 8; t++) if (idx >= 2 * t * (t - 1)) g = t;
  int rem = idx - 2 * g * (g - 1);
  int qi = rem / g;
  int c  = rem - qi * g;
  int qt = ((g - 1) << 2) + qi;

  int q0w = qt * 64 + wave * 32;   // 32 rows per wave
  const u16* Qb = qb  + (size_t)bh * 262144;
  const u16* Kb = kb  + (size_t)bh * 262144;
  const u16* Vb = vtb + (size_t)bh * 262144;

  // Two Q sub-tiles: A = rows q0w..+15, B = rows q0w+16..+31
  short8 aqA[4], aqB[4];
  {
    int t16 = q0w >> 4;
    #pragma unroll
    for (int cc = 0; cc < 4; cc++) {
      aqA[cc] = *(const short8*)&Qb[(size_t)((t16 * 16 + cc * 4 + quad) * 128 + lane16 * 8)];
      aqB[cc] = *(const short8*)&Qb[(size_t)(((t16 + 1) * 16 + cc * 4 + quad) * 128 + lane16 * 8)];
    }
  }

  int ktw   = (q0w >> 5) + 1;      // covers rows q0w..q0w+31 exactly (q0w % 32 == 0)
  int ktblk = qt * 2 + 2;
  int kt0   = c * 8;
  int kend  = min(min(kt0 + 8, ktblk), ktw);

  floatx4 oA[8], oB[8];
  #pragma unroll
  for (int j = 0; j < 8; j++) { oA[j] = (floatx4)(0.0f); oB[j] = (floatx4)(0.0f); }
  floatx4 olA = (floatx4)(0.0f), olB = (floatx4)(0.0f);

  short8 ones;
  #pragma unroll
  for (int e = 0; e < 8; e++) ones[e] = (short)0x3F80;

  int addrA = (lane16 + ((quad & 1) << 5)) << 2;
  int addrB = addrA + 64;
  int q_gA = q0w + lane16;
  int q_gB = q0w + 16 + lane16;

#define ATTN_TAIL(S0, S1, O_, OL_, QG, KT)                                                          \
  {                                                                                                 \
    int k0b = (KT) * 32 + quad * 4;                                                                 \
    _Pragma("unroll")                                                                               \
    for (int r = 0; r < 4; r++) {                                                                   \
      float p0 = exp2a(S0[r]);                                                                      \
      float p1 = exp2a(S1[r]);                                                                      \
      if (k0b + r > (QG)) p0 = 0.0f;                                                                \
      if (k0b + r + 16 > (QG)) p1 = 0.0f;                                                           \
      S0[r] = p0; S1[r] = p1;                                                                       \
    }                                                                                               \
    uint32_t x0 = __builtin_amdgcn_perm(__float_as_uint(S0[1]), __float_as_uint(S0[0]), 0x07060302u); \
    uint32_t x1 = __builtin_amdgcn_perm(__float_as_uint(S0[3]), __float_as_uint(S0[2]), 0x07060302u); \
    uint32_t y0 = __builtin_amdgcn_perm(__float_as_uint(S1[1]), __float_as_uint(S1[0]), 0x07060302u); \
    uint32_t y1 = __builtin_amdgcn_perm(__float_as_uint(S1[3]), __float_as_uint(S1[2]), 0x07060302u); \
    int pAx0 = __builtin_amdgcn_ds_bpermute(addrA, (int)x0);                                        \
    int pAx1 = __builtin_amdgcn_ds_bpermute(addrA, (int)x1);                                        \
    int pBx0 = __builtin_amdgcn_ds_bpermute(addrB, (int)x0);                                        \
    int pBx1 = __builtin_amdgcn_ds_bpermute(addrB, (int)x1);                                        \
    int pAy0 = __builtin_amdgcn_ds_bpermute(addrA, (int)y0);                                        \
    int pAy1 = __builtin_amdgcn_ds_bpermute(addrA, (int)y1);                                        \
    int pBy0 = __builtin_amdgcn_ds_bpermute(addrB, (int)y0);                                        \
    int pBy1 = __builtin_amdgcn_ds_bpermute(addrB, (int)y1);                                        \
    union { uint32_t u[4]; short8 s; } pf;                                                          \
    bool hi = quad >= 2;                                                                            \
    pf.u[0] = (uint32_t)(hi ? pAy0 : pAx0);                                                         \
    pf.u[1] = (uint32_t)(hi ? pAy1 : pAx1);                                                         \
    pf.u[2] = (uint32_t)(hi ? pBy0 : pBx0);                                                         \
    pf.u[3] = (uint32_t)(hi ? pBy1 : pBx1);                                                         \
    _Pragma("unroll")                                                                               \
    for (int j = 0; j < 8; j++)                                                                     \
      O_[j] = __builtin_amdgcn_mfma_f32_16x16x32_bf16(pf.s, vfr[j], O_[j], 0, 0, 0);                \
    OL_ = __builtin_amdgcn_mfma_f32_16x16x32_bf16(pf.s, ones, OL_, 0, 0, 0);                        \
  }

  for (int kt = kt0; kt < kend; kt++) {
    const u16* kp = Kb + (size_t)kt * 4096 + lane * 8;
    const u16* vp = Vb + (size_t)kt * 4096 + lane * 8;
    // K fragments (8 loads) feed BOTH Q sub-tiles
    short8 k0f[4], k1f[4];
    #pragma unroll
    for (int cc = 0; cc < 4; cc++) {
      k0f[cc] = *(const short8*)&kp[cc * 512];
      k1f[cc] = *(const short8*)&kp[(4 + cc) * 512];
    }

    floatx4 sA0 = (floatx4)(0.0f), sA1 = (floatx4)(0.0f);
    floatx4 sB0 = (floatx4)(0.0f), sB1 = (floatx4)(0.0f);
    #pragma unroll
    for (int cc = 0; cc < 4; cc++) {
      sA0 = __builtin_amdgcn_mfma_f32_16x16x32_bf16(k0f[cc], aqA[cc], sA0, 0, 0, 0);
      sA1 = __builtin_amdgcn_mfma_f32_16x16x32_bf16(k1f[cc], aqA[cc], sA1, 0, 0, 0);
      sB0 = __builtin_amdgcn_mfma_f32_16x16x32_bf16(k0f[cc], aqB[cc], sB0, 0, 0, 0);
      sB1 = __builtin_amdgcn_mfma_f32_16x16x32_bf16(k1f[cc], aqB[cc], sB1, 0, 0, 0);
    }

    // V fragments (8 loads) feed BOTH sub-tiles
    short8 vfr[8];
    #pragma unroll
    for (int j = 0; j < 8; j++)
      vfr[j] = *(const short8*)&vp[j * 512];

    ATTN_TAIL(sA0, sA1, oA, olA, q_gA, kt);
    ATTN_TAIL(sB0, sB1, oB, olB, q_gB, kt);
  }
#undef ATTN_TAIL

  int slot = bh * 144 + 2 * g * (g - 1) + qi * g + c;
  u16* pob = po + (size_t)slot * 8192;
  #pragma unroll
  for (int r = 0; r < 4; r++) {
    int qrA = wave * 32 + quad * 4 + r;
    int qrB = qrA + 16;
    #pragma unroll
    for (int j = 0; j < 8; j++) {
      pob[qrA * 128 + j * 16 + lane16] = f2bf(oA[j][r]);
      pob[qrB * 128 + j * 16 + lane16] = f2bf(oB[j][r]);
    }
    if (lane16 == 0) {
      pl[slot * 64 + qrA] = olA[r];
      pl[slot * 64 + qrB] = olB[r];
    }
  }
}

// ---------------- reduce: R11 slot mapping (frozen) ----------------
__global__ __launch_bounds__(256) void reduce_kernel(const u16* __restrict__ po,
                                                     const float* __restrict__ pl,
                                                     u16* __restrict__ attn) {
  int bh = blockIdx.x >> 5, qt = blockIdx.x & 31;
  int tid = threadIdx.x;
  int g = (qt >> 2) + 1;
  int slot0 = bh * 144 + 2 * g * (g - 1) + (qt & 3) * g;
  int qrow = tid >> 2;
  int d0 = (tid & 3) * 32;
  float acc[32];
  #pragma unroll
  for (int i = 0; i < 32; i++) acc[i] = 0.0f;
  float l = 0.0f;
  for (int c = 0; c < g; c++) {
    int slot = slot0 + c;
    l += pl[slot * 64 + qrow];
    const short8* p = (const short8*)(po + (size_t)slot * 8192 + qrow * 128 + d0);
    #pragma unroll
    for (int v = 0; v < 4; v++) {
      short8 pk = p[v];
      #pragma unroll
      for (int e = 0; e < 8; e++) acc[v * 8 + e] += bf2f((u16)pk[e]);
    }
  }
  float inv = rcpa(l);
  int b = bh >> 2, h = bh & 3, t = qt * 64 + qrow;
  u16* orow = attn + ((size_t)(b * TSEQ + t)) * CMOD + h * HD + d0;
  #pragma unroll
  for (int v = 0; v < 4; v++) {
    short8 ov;
    #pragma unroll
    for (int e = 0; e < 8; e++) ov[e] = (short)f2bf(acc[v * 8 + e] * inv);
    *(short8*)(orow + v * 8) = ov;
  }
}

extern "C" void kernel_launch(void* const* d_in, const int* in_sizes, int n_in,
                              void* d_out, int out_size, void* d_ws, size_t ws_size,
                              hipStream_t stream) {
  const float* x     = (const float*)d_in[0];
  const float* ln1g  = (const float*)d_in[1];
  const float* ln1b  = (const float*)d_in[2];
  const float* wqkv  = (const float*)d_in[3];
  const float* wproj = (const float*)d_in[4];
  const float* ln2g  = (const float*)d_in[5];
  const float* ln2b  = (const float*)d_in[6];
  const float* wff1  = (const float*)d_in[7];
  const float* wff2  = (const float*)d_in[8];
  float* out = (float*)d_out;
  char* ws = (char*)d_ws;

  u16* wt_qkv  = (u16*)(ws);
  u16* wt_proj = (u16*)(ws + 1572864);
  u16* wt_ff1  = (u16*)(ws + 2097152);
  u16* wt_ff2  = (u16*)(ws + 4194304);
  u16* ln_buf  = (u16*)(ws + 6291456);
  u16* q_buf   = (u16*)(ws + 14680064);
  u16* k_buf   = (u16*)(ws + 23068672);
  u16* vt_buf  = (u16*)(ws + 31457280);
  u16* attn    = (u16*)(ws + 39845888);
  float* x2    = (float*)(ws + 48234496);
  u16* h1      = (u16*)(ws + 65011712);
  // po: 2304 slots x 16KB = 37,748,736 B (overlaps x2/h1 region; stream-ordered safe)
  u16* po      = (u16*)(ws + 48234496);
  float* pl    = (float*)(ws + 85983232);

  dim3 blk(256);
  prep_kernel<<<dim3(5120), blk, 0, stream>>>(x, ln1g, ln1b, wqkv, wproj, wff1, wff2,
                                              ln_buf, wt_qkv, wt_proj, wt_ff1, wt_ff2);

  // QKV: TM=128,TN=64, grid 24x64 = 1536 blocks
  gemm_kernel<0, 128, 64, 6><<<dim3(CQKV / 64, BT / 128), blk, 0, stream>>>(
      ln_buf, wt_qkv, CMOD, nullptr, nullptr, q_buf, k_buf, vt_buf);

  // attn: grid 2304 x 128 threads (2 waves x 32 q-rows), XCD swizzle (bh = n & 15)
  attn_kernel<<<dim3(2304), dim3(128), 0, stream>>>(q_buf, k_buf, vt_buf, po, pl);

  reduce_kernel<<<dim3(512), blk, 0, stream>>>(po, pl, attn);

  // proj: TM=128,TN=64, grid 8x64 = 512 blocks
  gemm_kernel<1, 128, 64, 4><<<dim3(CMOD / 64, BT / 128), blk, 0, stream>>>(
      attn, wt_proj, CMOD, x, x2, nullptr, nullptr, nullptr);

  ln_kernel<<<dim3(BT / 4), blk, 0, stream>>>(x2, ln2g, ln2b, ln_buf);

  // FF1: TM=128,TN=64, grid 32x64 = 2048 blocks
  gemm_kernel<2, 128, 64, 6><<<dim3(DFF / 64, BT / 128), blk, 0, stream>>>(
      ln_buf, wt_ff1, CMOD, nullptr, nullptr, h1, nullptr, nullptr);

  // FF2: TM=128,TN=64, grid 8x64 = 512 blocks
  gemm_kernel<3, 128, 64, 4><<<dim3(CMOD / 64, BT / 128), blk, 0, stream>>>(
      h1, wt_ff2, DFF, x2, out, nullptr, nullptr, nullptr);
}

// Round 13
// 250.406 us; speedup vs baseline: 1.1281x; 1.0583x over previous
//
#include <hip/hip_runtime.h>
#include <cstdint>

typedef unsigned short u16;
typedef __attribute__((ext_vector_type(8))) short short8;
typedef __attribute__((ext_vector_type(4))) float floatx4;

#define BT    8192
#define TSEQ  2048
#define NBAT  4
#define CMOD  512
#define NH    4
#define HD    128
#define DFF   2048
#define CQKV  1536

__device__ __forceinline__ u16 f2bf(float f) {
  union { float f; uint32_t u; } v; v.f = f;
  uint32_t r = v.u + 0x7FFFu + ((v.u >> 16) & 1u);
  return (u16)(r >> 16);
}
__device__ __forceinline__ float bf2f(u16 u) {
  union { uint32_t u; float f; } v; v.u = ((uint32_t)u) << 16; return v.f;
}
__device__ __forceinline__ float exp2a(float x) {
  float r; asm("v_exp_f32 %0, %1" : "=v"(r) : "v"(x)); return r;
}
__device__ __forceinline__ float rcpa(float x) {
  float r; asm("v_rcp_f32 %0, %1" : "=v"(r) : "v"(x)); return r;
}

typedef __attribute__((address_space(1))) const unsigned int ga_u32;
typedef __attribute__((address_space(3))) unsigned int ls_u32;
__device__ __forceinline__ void glds16(const u16* g, u16* l) {
  __builtin_amdgcn_global_load_lds((ga_u32*)g, (ls_u32*)l, 16, 0, 0);
}

// ---------------- fused prep: 4 weight transposes + LN1 (frozen) ----------------
__device__ __forceinline__ void tcast_body(const float* __restrict__ W, u16* __restrict__ Wt,
                                           int K, int N, int bx, int by, int tid,
                                           float (*tile)[33]) {
  int n0 = bx * 32, k0 = by * 32;
  int tx = tid & 31, ty = tid >> 5;
  #pragma unroll
  for (int r = 0; r < 32; r += 8)
    tile[r + ty][tx] = W[(size_t)(k0 + r + ty) * N + n0 + tx];
  __syncthreads();
  #pragma unroll
  for (int r = 0; r < 32; r += 8)
    Wt[(size_t)(n0 + r + ty) * K + k0 + tx] = f2bf(tile[tx][r + ty]);
}

__global__ __launch_bounds__(256) void prep_kernel(
    const float* __restrict__ x, const float* __restrict__ g, const float* __restrict__ b,
    const float* __restrict__ wqkv, const float* __restrict__ wproj,
    const float* __restrict__ wff1, const float* __restrict__ wff2,
    u16* __restrict__ ln_out, u16* __restrict__ wqkvT, u16* __restrict__ wprojT,
    u16* __restrict__ wff1T, u16* __restrict__ wff2T) {
  __shared__ float tile[32][33];
  int bid = blockIdx.x, tid = threadIdx.x;
  if (bid < 768) {
    tcast_body(wqkv, wqkvT, CMOD, CQKV, bid % 48, bid / 48, tid, tile);
  } else if (bid < 1024) {
    int id = bid - 768; tcast_body(wproj, wprojT, CMOD, CMOD, id % 16, id / 16, tid, tile);
  } else if (bid < 2048) {
    int id = bid - 1024; tcast_body(wff1, wff1T, CMOD, DFF, id % 64, id / 64, tid, tile);
  } else if (bid < 3072) {
    int id = bid - 2048; tcast_body(wff2, wff2T, DFF, CMOD, id % 16, id / 16, tid, tile);
  } else {
    int row = (bid - 3072) * 4 + (tid >> 6);
    int lane = tid & 63;
    const float4* xr = (const float4*)(x + (size_t)row * CMOD);
    float4 a = xr[lane], c = xr[lane + 64];
    float s = a.x + a.y + a.z + a.w + c.x + c.y + c.z + c.w;
    float q = a.x*a.x + a.y*a.y + a.z*a.z + a.w*a.w
            + c.x*c.x + c.y*c.y + c.z*c.z + c.w*c.w;
    #pragma unroll
    for (int o = 32; o; o >>= 1) { s += __shfl_xor(s, o); q += __shfl_xor(q, o); }
    float mu = s * (1.0f / CMOD);
    float rstd = rsqrtf(q * (1.0f / CMOD) - mu * mu + 1e-5f);
    const float4* gr = (const float4*)g;
    const float4* br = (const float4*)b;
    float4 g0 = gr[lane], g1 = gr[lane + 64], b0 = br[lane], b1 = br[lane + 64];
    u16* orow = ln_out + (size_t)row * CMOD;
    int i0 = lane * 4, i1 = (lane + 64) * 4;
    orow[i0 + 0] = f2bf((a.x - mu) * rstd * g0.x + b0.x);
    orow[i0 + 1] = f2bf((a.y - mu) * rstd * g0.y + b0.y);
    orow[i0 + 2] = f2bf((a.z - mu) * rstd * g0.z + b0.z);
    orow[i0 + 3] = f2bf((a.w - mu) * rstd * g0.w + b0.w);
    orow[i1 + 0] = f2bf((c.x - mu) * rstd * g1.x + b1.x);
    orow[i1 + 1] = f2bf((c.y - mu) * rstd * g1.y + b1.y);
    orow[i1 + 2] = f2bf((c.z - mu) * rstd * g1.z + b1.z);
    orow[i1 + 3] = f2bf((c.w - mu) * rstd * g1.w + b1.w);
  }
}

// ---------------- layernorm (standalone, for LN2; frozen) ----------------
__global__ __launch_bounds__(256) void ln_kernel(const float* __restrict__ x,
                                                 const float* __restrict__ g,
                                                 const float* __restrict__ b,
                                                 u16* __restrict__ out) {
  int row = blockIdx.x * 4 + (threadIdx.x >> 6);
  int lane = threadIdx.x & 63;
  const float4* xr = (const float4*)(x + (size_t)row * CMOD);
  float4 a = xr[lane], c = xr[lane + 64];
  float s = a.x + a.y + a.z + a.w + c.x + c.y + c.z + c.w;
  float q = a.x*a.x + a.y*a.y + a.z*a.z + a.w*a.w
          + c.x*c.x + c.y*c.y + c.z*c.z + c.w*c.w;
  #pragma unroll
  for (int o = 32; o; o >>= 1) { s += __shfl_xor(s, o); q += __shfl_xor(q, o); }
  float mu = s * (1.0f / CMOD);
  float rstd = rsqrtf(q * (1.0f / CMOD) - mu * mu + 1e-5f);
  const float4* gr = (const float4*)g;
  const float4* br = (const float4*)b;
  float4 g0 = gr[lane], g1 = gr[lane + 64], b0 = br[lane], b1 = br[lane + 64];
  u16* orow = out + (size_t)row * CMOD;
  int i0 = lane * 4, i1 = (lane + 64) * 4;
  orow[i0 + 0] = f2bf((a.x - mu) * rstd * g0.x + b0.x);
  orow[i0 + 1] = f2bf((a.y - mu) * rstd * g0.y + b0.y);
  orow[i0 + 2] = f2bf((a.z - mu) * rstd * g0.z + b0.z);
  orow[i0 + 3] = f2bf((a.w - mu) * rstd * g0.w + b0.w);
  orow[i1 + 0] = f2bf((c.x - mu) * rstd * g1.x + b1.x);
  orow[i1 + 1] = f2bf((c.y - mu) * rstd * g1.y + b1.y);
  orow[i1 + 2] = f2bf((c.z - mu) * rstd * g1.z + b1.z);
  orow[i1 + 3] = f2bf((c.w - mu) * rstd * g1.w + b1.w);
}

// ---------------- MFMA GEMM: R12 + XCD-co-locating 1D grid (THE ONLY CHANGE) ----------------
// R12 top dispatch = FF2: FETCH 140MB vs ideal 52MB. Cause: the 8 column-blocks
// sharing one 128-row A-panel (524KB) were dispatched 64 apart -> 8 different XCDs
// under round-robin -> each XCD streams the panel from HBM separately (268MB demand,
// L3 absorbs half). Fix (T1): 1D grid, m-block = n1d & 63, n-block = n1d >> 6 ->
// all sharers have the same n1d%8 -> one XCD; its L2 serves 7/8 panel reads.
// Pure index remap: math/accumulation unchanged -> bit-identical output.
template <int EPI, int TM, int TN, int MINW>
__global__ __launch_bounds__(256, MINW) void gemm_kernel(
    const u16* __restrict__ A, const u16* __restrict__ Bt, int K,
    const float* __restrict__ resid, float* __restrict__ outf,
    u16* __restrict__ ob0, u16* __restrict__ ob1, u16* __restrict__ ob2) {
  constexpr int MR  = TM / 32;
  constexpr int NR  = TN / 32;
  constexpr int NAR = TM / 64;
  constexpr int NBR = TN / 64;
  __shared__ __align__(16) u16 As[2][TM * 32];
  __shared__ __align__(16) u16 Bs[2][TN * 32];
  int tid = threadIdx.x;
  int lane = tid & 63, wave = tid >> 6;
  int lane16 = lane & 15, quad = lane >> 4;
  // 1D grid: 64 m-blocks (BT/128) in the low bits -> same A-panel => same XCD
  int n1d = blockIdx.x;
  int m0 = (n1d & 63) * TM;
  int n0 = (n1d >> 6) * TN;
  int wm = (wave >> 1) * (TM / 2), wn = (wave & 1) * (TN / 2);

  floatx4 acc[MR][NR];
  #pragma unroll
  for (int i = 0; i < MR; i++)
    #pragma unroll
    for (int j = 0; j < NR; j++) acc[i][j] = (floatx4)(0.0f);

  const u16* agp[NAR]; u16* alp[NAR][2];
  const u16* bgp[NBR]; u16* blp[NBR][2];
  #pragma unroll
  for (int i = 0; i < NAR; i++) {
    int s = i * 256 + tid;
    agp[i] = A + (size_t)(m0 + (s >> 2)) * K + (s & 3) * 8;
    alp[i][0] = &As[0][(i * 256 + wave * 64) * 8];
    alp[i][1] = &As[1][(i * 256 + wave * 64) * 8];
  }
  #pragma unroll
  for (int i = 0; i < NBR; i++) {
    int s = i * 256 + tid;
    bgp[i] = Bt + (size_t)(n0 + (s >> 2)) * K + (s & 3) * 8;
    blp[i][0] = &Bs[0][(i * 256 + wave * 64) * 8];
    blp[i][1] = &Bs[1][(i * 256 + wave * 64) * 8];
  }

  int nk = K >> 5;
  #pragma unroll
  for (int i = 0; i < NAR; i++) glds16(agp[i], alp[i][0]);
  #pragma unroll
  for (int i = 0; i < NBR; i++) glds16(bgp[i], blp[i][0]);

  for (int kt = 0; kt < nk; kt++) {
    __syncthreads();
    int buf = kt & 1;
    if (kt + 1 < nk) {
      int k1 = (kt + 1) * 32;
      #pragma unroll
      for (int i = 0; i < NAR; i++) glds16(agp[i] + k1, alp[i][buf ^ 1]);
      #pragma unroll
      for (int i = 0; i < NBR; i++) glds16(bgp[i] + k1, blp[i][buf ^ 1]);
    }
    short8 af[MR];
    #pragma unroll
    for (int i = 0; i < MR; i++)
      af[i] = *(const short8*)&As[buf][(wm + i * 16 + lane16) * 32 + quad * 8];
    #pragma unroll
    for (int j = 0; j < NR; j++) {
      short8 bfj = *(const short8*)&Bs[buf][(wn + j * 16 + lane16) * 32 + quad * 8];
      #pragma unroll
      for (int i = 0; i < MR; i++)
        acc[i][j] = __builtin_amdgcn_mfma_f32_16x16x32_bf16(af[i], bfj, acc[i][j], 0, 0, 0);
    }
  }

  #pragma unroll
  for (int i = 0; i < MR; i++) {
    #pragma unroll
    for (int j = 0; j < NR; j++) {
      #pragma unroll
      for (int r = 0; r < 4; r++) {
        int m = m0 + wm + i * 16 + quad * 4 + r;
        int n = n0 + wn + j * 16 + lane16;
        float v = acc[i][j][r];
        if (EPI == 0) {
          int bb = m >> 11, t = m & 2047;
          int nn = n & 511, which = n >> 9;
          int h = nn >> 7, d = nn & 127;
          size_t base = (size_t)(bb * NH + h) * 262144;
          if (which == 0) {
            int t16 = t >> 4, l16 = t & 15, cc = d >> 5, qd = (d >> 3) & 3, e = d & 7;
            ob0[base + (size_t)((t16 * 16 + cc * 4 + qd) * 128 + l16 * 8 + e)] = f2bf(v * 0.12751743f);
          } else if (which == 1) {
            int kt = t >> 5, hf = (t >> 4) & 1, l16 = t & 15, cc = d >> 5, qd = (d >> 3) & 3, e = d & 7;
            ob1[base + (size_t)((kt * 8 + hf * 4 + cc) * 512 + qd * 128 + l16 * 8 + e)] = f2bf(v);
          } else {
            int kt = t >> 5, qv = (t >> 3) & 3, e = t & 7, j2 = d >> 4, l16 = d & 15;
            ob2[base + (size_t)((kt * 8 + j2) * 512 + qv * 128 + l16 * 8 + e)] = f2bf(v);
          }
        } else if (EPI == 1) {
          size_t idx = (size_t)m * CMOD + n;
          outf[idx] = v + resid[idx];
        } else if (EPI == 2) {
          float ge = 0.5f * v * (1.0f + erff(v * 0.70710678118654752f));
          ob0[(size_t)m * DFF + n] = f2bf(ge);
        } else {
          size_t idx = (size_t)m * CMOD + n;
          outf[idx] = v + resid[idx];
        }
      }
    }
  }
}

// ---------------- flash attention: R12 (frozen) ----------------
__global__ __launch_bounds__(128) void attn_kernel(const u16* __restrict__ qb,
                                                   const u16* __restrict__ kb,
                                                   const u16* __restrict__ vtb,
                                                   u16* __restrict__ po,
                                                   float* __restrict__ pl) {
  int tid = threadIdx.x, wave = tid >> 6, lane = tid & 63;
  int lane16 = lane & 15, quad = lane >> 4;
  int n1d = blockIdx.x;
  int bh = n1d & 15;
  int idx = 143 - (n1d >> 4);   // heavy (large qt) chunks dispatch first
  int g = 1;
  #pragma unroll
  for (int t = 2; t <= 8; t++) if (idx >= 2 * t * (t - 1)) g = t;
  int rem = idx - 2 * g * (g - 1);
  int qi = rem / g;
  int c  = rem - qi * g;
  int qt = ((g - 1) << 2) + qi;

  int q0w = qt * 64 + wave * 32;   // 32 rows per wave
  const u16* Qb = qb  + (size_t)bh * 262144;
  const u16* Kb = kb  + (size_t)bh * 262144;
  const u16* Vb = vtb + (size_t)bh * 262144;

  short8 aqA[4], aqB[4];
  {
    int t16 = q0w >> 4;
    #pragma unroll
    for (int cc = 0; cc < 4; cc++) {
      aqA[cc] = *(const short8*)&Qb[(size_t)((t16 * 16 + cc * 4 + quad) * 128 + lane16 * 8)];
      aqB[cc] = *(const short8*)&Qb[(size_t)(((t16 + 1) * 16 + cc * 4 + quad) * 128 + lane16 * 8)];
    }
  }

  int ktw   = (q0w >> 5) + 1;
  int ktblk = qt * 2 + 2;
  int kt0   = c * 8;
  int kend  = min(min(kt0 + 8, ktblk), ktw);

  floatx4 oA[8], oB[8];
  #pragma unroll
  for (int j = 0; j < 8; j++) { oA[j] = (floatx4)(0.0f); oB[j] = (floatx4)(0.0f); }
  floatx4 olA = (floatx4)(0.0f), olB = (floatx4)(0.0f);

  short8 ones;
  #pragma unroll
  for (int e = 0; e < 8; e++) ones[e] = (short)0x3F80;

  int addrA = (lane16 + ((quad & 1) << 5)) << 2;
  int addrB = addrA + 64;
  int q_gA = q0w + lane16;
  int q_gB = q0w + 16 + lane16;

#define ATTN_TAIL(S0, S1, O_, OL_, QG, KT)                                                          \
  {                                                                                                 \
    int k0b = (KT) * 32 + quad * 4;                                                                 \
    _Pragma("unroll")                                                                               \
    for (int r = 0; r < 4; r++) {                                                                   \
      float p0 = exp2a(S0[r]);                                                                      \
      float p1 = exp2a(S1[r]);                                                                      \
      if (k0b + r > (QG)) p0 = 0.0f;                                                                \
      if (k0b + r + 16 > (QG)) p1 = 0.0f;                                                           \
      S0[r] = p0; S1[r] = p1;                                                                       \
    }                                                                                               \
    uint32_t x0 = __builtin_amdgcn_perm(__float_as_uint(S0[1]), __float_as_uint(S0[0]), 0x07060302u); \
    uint32_t x1 = __builtin_amdgcn_perm(__float_as_uint(S0[3]), __float_as_uint(S0[2]), 0x07060302u); \
    uint32_t y0 = __builtin_amdgcn_perm(__float_as_uint(S1[1]), __float_as_uint(S1[0]), 0x07060302u); \
    uint32_t y1 = __builtin_amdgcn_perm(__float_as_uint(S1[3]), __float_as_uint(S1[2]), 0x07060302u); \
    int pAx0 = __builtin_amdgcn_ds_bpermute(addrA, (int)x0);                                        \
    int pAx1 = __builtin_amdgcn_ds_bpermute(addrA, (int)x1);                                        \
    int pBx0 = __builtin_amdgcn_ds_bpermute(addrB, (int)x0);                                        \
    int pBx1 = __builtin_amdgcn_ds_bpermute(addrB, (int)x1);                                        \
    int pAy0 = __builtin_amdgcn_ds_bpermute(addrA, (int)y0);                                        \
    int pAy1 = __builtin_amdgcn_ds_bpermute(addrA, (int)y1);                                        \
    int pBy0 = __builtin_amdgcn_ds_bpermute(addrB, (int)y0);                                        \
    int pBy1 = __builtin_amdgcn_ds_bpermute(addrB, (int)y1);                                        \
    union { uint32_t u[4]; short8 s; } pf;                                                          \
    bool hi = quad >= 2;                                                                            \
    pf.u[0] = (uint32_t)(hi ? pAy0 : pAx0);                                                         \
    pf.u[1] = (uint32_t)(hi ? pAy1 : pAx1);                                                         \
    pf.u[2] = (uint32_t)(hi ? pBy0 : pBx0);                                                         \
    pf.u[3] = (uint32_t)(hi ? pBy1 : pBx1);                                                         \
    _Pragma("unroll")                                                                               \
    for (int j = 0; j < 8; j++)                                                                     \
      O_[j] = __builtin_amdgcn_mfma_f32_16x16x32_bf16(pf.s, vfr[j], O_[j], 0, 0, 0);                \
    OL_ = __builtin_amdgcn_mfma_f32_16x16x32_bf16(pf.s, ones, OL_, 0, 0, 0);                        \
  }

  for (int kt = kt0; kt < kend; kt++) {
    const u16* kp = Kb + (size_t)kt * 4096 + lane * 8;
    const u16* vp = Vb + (size_t)kt * 4096 + lane * 8;
    short8 k0f[4], k1f[4];
    #pragma unroll
    for (int cc = 0; cc < 4; cc++) {
      k0f[cc] = *(const short8*)&kp[cc * 512];
      k1f[cc] = *(const short8*)&kp[(4 + cc) * 512];
    }

    floatx4 sA0 = (floatx4)(0.0f), sA1 = (floatx4)(0.0f);
    floatx4 sB0 = (floatx4)(0.0f), sB1 = (floatx4)(0.0f);
    #pragma unroll
    for (int cc = 0; cc < 4; cc++) {
      sA0 = __builtin_amdgcn_mfma_f32_16x16x32_bf16(k0f[cc], aqA[cc], sA0, 0, 0, 0);
      sA1 = __builtin_amdgcn_mfma_f32_16x16x32_bf16(k1f[cc], aqA[cc], sA1, 0, 0, 0);
      sB0 = __builtin_amdgcn_mfma_f32_16x16x32_bf16(k0f[cc], aqB[cc], sB0, 0, 0, 0);
      sB1 = __builtin_amdgcn_mfma_f32_16x16x32_bf16(k1f[cc], aqB[cc], sB1, 0, 0, 0);
    }

    short8 vfr[8];
    #pragma unroll
    for (int j = 0; j < 8; j++)
      vfr[j] = *(const short8*)&vp[j * 512];

    ATTN_TAIL(sA0, sA1, oA, olA, q_gA, kt);
    ATTN_TAIL(sB0, sB1, oB, olB, q_gB, kt);
  }
#undef ATTN_TAIL

  int slot = bh * 144 + 2 * g * (g - 1) + qi * g + c;
  u16* pob = po + (size_t)slot * 8192;
  #pragma unroll
  for (int r = 0; r < 4; r++) {
    int qrA = wave * 32 + quad * 4 + r;
    int qrB = qrA + 16;
    #pragma unroll
    for (int j = 0; j < 8; j++) {
      pob[qrA * 128 + j * 16 + lane16] = f2bf(oA[j][r]);
      pob[qrB * 128 + j * 16 + lane16] = f2bf(oB[j][r]);
    }
    if (lane16 == 0) {
      pl[slot * 64 + qrA] = olA[r];
      pl[slot * 64 + qrB] = olB[r];
    }
  }
}

// ---------------- reduce: R11 slot mapping (frozen) ----------------
__global__ __launch_bounds__(256) void reduce_kernel(const u16* __restrict__ po,
                                                     const float* __restrict__ pl,
                                                     u16* __restrict__ attn) {
  int bh = blockIdx.x >> 5, qt = blockIdx.x & 31;
  int tid = threadIdx.x;
  int g = (qt >> 2) + 1;
  int slot0 = bh * 144 + 2 * g * (g - 1) + (qt & 3) * g;
  int qrow = tid >> 2;
  int d0 = (tid & 3) * 32;
  float acc[32];
  #pragma unroll
  for (int i = 0; i < 32; i++) acc[i] = 0.0f;
  float l = 0.0f;
  for (int c = 0; c < g; c++) {
    int slot = slot0 + c;
    l += pl[slot * 64 + qrow];
    const short8* p = (const short8*)(po + (size_t)slot * 8192 + qrow * 128 + d0);
    #pragma unroll
    for (int v = 0; v < 4; v++) {
      short8 pk = p[v];
      #pragma unroll
      for (int e = 0; e < 8; e++) acc[v * 8 + e] += bf2f((u16)pk[e]);
    }
  }
  float inv = rcpa(l);
  int b = bh >> 2, h = bh & 3, t = qt * 64 + qrow;
  u16* orow = attn + ((size_t)(b * TSEQ + t)) * CMOD + h * HD + d0;
  #pragma unroll
  for (int v = 0; v < 4; v++) {
    short8 ov;
    #pragma unroll
    for (int e = 0; e < 8; e++) ov[e] = (short)f2bf(acc[v * 8 + e] * inv);
    *(short8*)(orow + v * 8) = ov;
  }
}

extern "C" void kernel_launch(void* const* d_in, const int* in_sizes, int n_in,
                              void* d_out, int out_size, void* d_ws, size_t ws_size,
                              hipStream_t stream) {
  const float* x     = (const float*)d_in[0];
  const float* ln1g  = (const float*)d_in[1];
  const float* ln1b  = (const float*)d_in[2];
  const float* wqkv  = (const float*)d_in[3];
  const float* wproj = (const float*)d_in[4];
  const float* ln2g  = (const float*)d_in[5];
  const float* ln2b  = (const float*)d_in[6];
  const float* wff1  = (const float*)d_in[7];
  const float* wff2  = (const float*)d_in[8];
  float* out = (float*)d_out;
  char* ws = (char*)d_ws;

  u16* wt_qkv  = (u16*)(ws);
  u16* wt_proj = (u16*)(ws + 1572864);
  u16* wt_ff1  = (u16*)(ws + 2097152);
  u16* wt_ff2  = (u16*)(ws + 4194304);
  u16* ln_buf  = (u16*)(ws + 6291456);
  u16* q_buf   = (u16*)(ws + 14680064);
  u16* k_buf   = (u16*)(ws + 23068672);
  u16* vt_buf  = (u16*)(ws + 31457280);
  u16* attn    = (u16*)(ws + 39845888);
  float* x2    = (float*)(ws + 48234496);
  u16* h1      = (u16*)(ws + 65011712);
  u16* po      = (u16*)(ws + 48234496);
  float* pl    = (float*)(ws + 85983232);

  dim3 blk(256);
  prep_kernel<<<dim3(5120), blk, 0, stream>>>(x, ln1g, ln1b, wqkv, wproj, wff1, wff2,
                                              ln_buf, wt_qkv, wt_proj, wt_ff1, wt_ff2);

  // QKV: 1D grid 24*64 (m-block in low 6 bits -> panel-sharing blocks on one XCD)
  gemm_kernel<0, 128, 64, 6><<<dim3((CQKV / 64) * 64), blk, 0, stream>>>(
      ln_buf, wt_qkv, CMOD, nullptr, nullptr, q_buf, k_buf, vt_buf);

  // attn: grid 2304 x 128 threads (2 waves x 32 q-rows), XCD swizzle (bh = n & 15)
  attn_kernel<<<dim3(2304), dim3(128), 0, stream>>>(q_buf, k_buf, vt_buf, po, pl);

  reduce_kernel<<<dim3(512), blk, 0, stream>>>(po, pl, attn);

  // proj: 1D grid 8*64
  gemm_kernel<1, 128, 64, 4><<<dim3((CMOD / 64) * 64), blk, 0, stream>>>(
      attn, wt_proj, CMOD, x, x2, nullptr, nullptr, nullptr);

  ln_kernel<<<dim3(BT / 4), blk, 0, stream>>>(x2, ln2g, ln2b, ln_buf);

  // FF1: 1D grid 32*64
  gemm_kernel<2, 128, 64, 6><<<dim3((DFF / 64) * 64), blk, 0, stream>>>(
      ln_buf, wt_ff1, CMOD, nullptr, nullptr, h1, nullptr, nullptr);

  // FF2: 1D grid 8*64
  gemm_kernel<3, 128, 64, 4><<<dim3((CMOD / 64) * 64), blk, 0, stream>>>(
      h1, wt_ff2, DFF, x2, out, nullptr, nullptr, nullptr);
}